// Round 11
// 308.889 us; speedup vs baseline: 4.0633x; 1.0644x over previous
//
#include <hip/hip_runtime.h>
#include <hip/hip_fp16.h>

#define N_NODES 10000
#define N_EDGES 160000
#define N_GRAPHS 16

typedef __attribute__((ext_vector_type(8))) _Float16 f16x8;
typedef __attribute__((ext_vector_type(4))) float f32x4;
typedef __attribute__((ext_vector_type(4))) unsigned short u16x4;
typedef __attribute__((ext_vector_type(2))) unsigned short u16x2;
typedef unsigned int uint32;
typedef unsigned short u16;

// ---- workspace layout (float offsets) ----
#define OFF_ES8  0
#define OFF_SHV  (OFF_ES8 + N_EDGES*8)
#define OFF_S    (OFF_SHV + N_EDGES*3)
#define OFF_H    (OFF_S   + N_NODES*128)
#define OFF_GS   (OFF_H   + N_NODES*128)
#define OFF_HS   (OFF_GS  + N_NODES*64)
#define OFF_HV   (OFF_HS  + N_NODES*64)
#define OFF_NS   (OFF_HV  + N_NODES*192)   /* fallback zero-region start */
#define OFF_NV   (OFF_NS  + N_NODES*128)
#define OFF_NMID (OFF_NV  + N_NODES*384)
#define OFF_POOL (OFF_NMID+ N_NODES*128)   /* new-path zero-region start */
#define OFF_CNT  (OFF_POOL+ N_GRAPHS*128)
#define OFF_HIST (OFF_CNT + N_GRAPHS)
#define OFF_CURS (OFF_HIST+ N_NODES)
#define OFF_OFFS (OFF_CURS+ N_NODES)       /* new-path zero-region end (excl) */
#define OFF_FRAG (OFF_OFFS+ N_NODES + 16)  /* persistent frags: 57344 u16 (f16 single-plane) */
#define OFF_SLOT (OFF_FRAG+ 57344)
#define OFF_WBUF (OFF_SLOT+ N_EDGES)
#define WBUF_FLOATS ((size_t)N_EDGES*256)
#define WS_NEED_BYTES ((size_t)(OFF_WBUF + WBUF_FLOATS) * 4)

// persistent frag sub-offsets in u16 (single-plane f16: NF*KS*512 each)
#define F_B1   0        /* conv1 L1: NF4 KS1 -> 2048  */
#define F_B2   2048     /* conv1 L2: NF4 KS2 -> 4096  */
#define F_B3   6144     /* conv1 L3: NF16 KS2 -> 16384 */
#define F_B1b  22528
#define F_B2b  24576
#define F_B3b  28672    /* conv2 L3: NF8 KS2 -> 8192 */
#define F_WE   36864    /* W_embed: NF8 KS1 -> 4096 */
#define F_L1   40960    /* c1_lin1: NF8 KS4 -> 16384 */
#define FRAG_TOT 57344

// node-frag sub-offsets in u16
#define NF_WLS 0        /* c1_lin2_s: NF8 KS4 -> 16384 */
#define NF_C1  16384    /* c1_sc:   NF128 KS4 -> 262144 */
#define NF_W2  278528   /* c2_lin2:  NF8 KS4 -> 16384 */
#define NF_C2  294912   /* c2_sc:   NF128 KS2 -> 131072 */
#define NF_LV  425984   /* c1_lin2_v: NF4 KS4 -> 8192 */
#define NF_2S  434176   /* c2_lin1_s: NF4 KS2 -> 4096 */
#define NF_2V  438272   /* c2_lin1_v: NF4 KS2 -> 4096 */
#define NFRAG_TOT 442368

#define NM128 (N_NODES*128)

#define INV_SQRT32   0.17677669529663687f
#define INV_SQRT128  0.08838834764831845f
#define INV_SQRT8    0.3535533905932738f
#define INV_SQRT64   0.125f
#define INV_SQRT2048 0.022097086912079608f
#define INV_SQRT1024 0.03125f
#define INV_SQRT10   0.31622776601683794f
#define INV_SQRT3    0.5773502691896258f
#define SQRT3_C      1.7320508075688772f

__device__ __forceinline__ float siluf(float x){ return x / (1.f + __expf(-x)); }
__device__ __forceinline__ float sigf (float x){ return 1.f / (1.f + __expf(-x)); }
__device__ __forceinline__ u16 f2h(float x){ return __half_as_ushort(__float2half_rn(x)); }
__device__ __forceinline__ float h2f(u16 b){ return __half2float(__ushort_as_half(b)); }
__device__ __forceinline__ f16x8 cvt8(const float* __restrict__ p) {
  f32x4 v0 = *(const f32x4*)p;
  f32x4 v1 = *(const f32x4*)(p + 4);
  f16x8 r;
  r[0]=(_Float16)v0[0]; r[1]=(_Float16)v0[1]; r[2]=(_Float16)v0[2]; r[3]=(_Float16)v0[3];
  r[4]=(_Float16)v1[0]; r[5]=(_Float16)v1[1]; r[6]=(_Float16)v1[2]; r[7]=(_Float16)v1[3];
  return r;
}

__device__ __forceinline__ void geom_core(const float* __restrict__ ev,
                                          float* __restrict__ es, float* __restrict__ sv) {
  float vx = ev[0], vy = ev[1], vz = ev[2];
  float d  = sqrtf(vx*vx + vy*vy + vz*vz);
  float xs = d - 0.25f;
  bool  in = (xs > 0.f) && (xs < 4.0f);
  float safe = xs > 0.f ? xs : 1.f;
  float amp  = in ? 2.0f/safe : 0.f;
  const float PI4 = 0.7853981633974483f;
  #pragma unroll
  for (int k = 0; k < 8; ++k)
    es[k] = amp * sinf((float)(k+1) * PI4 * safe);
  float invd = d > 0.f ? 1.f/d : 1.f;
  sv[0] = SQRT3_C*vx*invd;
  sv[1] = SQRT3_C*vy*invd;
  sv[2] = SQRT3_C*vz*invd;
}

// ---------------- edge geometry, CSR-permuted: es8[p]/shv[p] = geom(evec[slot[p]]) ----------------
__global__ void k_geom_csr(const float* __restrict__ evec, const int* __restrict__ slot,
                           float* __restrict__ es8, float* __restrict__ shv) {
  int p = blockIdx.x*256 + threadIdx.x;
  if (p >= N_EDGES) return;
  int e = slot[p];
  float es[8], sv[3];
  geom_core(evec + (size_t)e*3, es, sv);
  #pragma unroll
  for (int k = 0; k < 8; ++k) es8[(size_t)p*8+k] = es[k];
  shv[(size_t)p*3+0] = sv[0]; shv[(size_t)p*3+1] = sv[1]; shv[(size_t)p*3+2] = sv[2];
}

// ---------------- edge geometry, identity order (fallback path) ----------------
__global__ void k_geom_id(const float* __restrict__ evec,
                          float* __restrict__ es8, float* __restrict__ shv) {
  int e = blockIdx.x*256 + threadIdx.x;
  if (e >= N_EDGES) return;
  float es[8], sv[3];
  geom_core(evec + (size_t)e*3, es, sv);
  #pragma unroll
  for (int k = 0; k < 8; ++k) es8[(size_t)e*8+k] = es[k];
  shv[(size_t)e*3+0] = sv[0]; shv[(size_t)e*3+1] = sv[1]; shv[(size_t)e*3+2] = sv[2];
}

// ---------------- fallback scalar linear ----------------
__global__ void k_linear128(const float* __restrict__ A, const float* __restrict__ W,
                            float* __restrict__ O, int K, float scale, int total) {
  int t = blockIdx.x*256 + threadIdx.x;
  if (t >= total) return;
  int n = t >> 7, j = t & 127;
  const float* a = A + n*K;
  float a0=0.f,a1=0.f,a2=0.f,a3=0.f;
  for (int k = 0; k < K; k += 4) {
    a0 += a[k+0]*W[(k+0)*128+j];
    a1 += a[k+1]*W[(k+1)*128+j];
    a2 += a[k+2]*W[(k+2)*128+j];
    a3 += a[k+3]*W[(k+3)*128+j];
  }
  O[t] = (a0+a1+a2+a3)*scale;
}

// ---------------- graph node counts + edge histogram (merged) ----------------
__global__ void k_cnthist(const int* __restrict__ batch, const int* __restrict__ edst,
                          float* __restrict__ cnt, int* __restrict__ hist) {
  __shared__ int lc[N_GRAPHS];
  int t = threadIdx.x;
  if (t < N_GRAPHS) lc[t] = 0;
  __syncthreads();
  int i = blockIdx.x*256 + t;
  if (i < N_NODES) atomicAdd(&lc[batch[i]], 1);
  if (i < N_EDGES) atomicAdd(&hist[edst[i]], 1);
  __syncthreads();
  if (t < N_GRAPHS && lc[t] > 0) atomicAdd(&cnt[t], (float)lc[t]);
}

__global__ __launch_bounds__(1024) void k_scanp(const int* __restrict__ hist,
                                                int* __restrict__ offs) {
  __shared__ int wsum[16];
  const int t = threadIdx.x;
  const int lane = t & 63, w = t >> 6;
  const int base = t*10;
  int v[10]; int s = 0;
  #pragma unroll
  for (int i = 0; i < 10; ++i) {
    int idx = base + i;
    int x = (idx < N_NODES) ? hist[idx] : 0;
    s += x; v[i] = s;
  }
  int ws = s;
  #pragma unroll
  for (int d = 1; d < 64; d <<= 1) {
    int u = __shfl_up(ws, d);
    if (lane >= d) ws += u;
  }
  if (lane == 63) wsum[w] = ws;
  __syncthreads();
  if (w == 0) {
    int x = (lane < 16) ? wsum[lane] : 0;
    #pragma unroll
    for (int d = 1; d < 16; d <<= 1) {
      int u = __shfl_up(x, d);
      if (lane >= d) x += u;
    }
    if (lane < 16) wsum[lane] = x;
  }
  __syncthreads();
  int waveoff = (w > 0) ? wsum[w-1] : 0;
  int texcl = waveoff + ws - s;
  if (t == 0) offs[0] = 0;
  #pragma unroll
  for (int i = 0; i < 10; ++i) {
    int idx = base + i;
    if (idx < N_NODES) offs[idx+1] = texcl + v[i];
  }
}

// slot + permuted esrc
__global__ void k_slot(const int* __restrict__ edst, const int* __restrict__ esrc,
                       const int* __restrict__ offs,
                       int* __restrict__ curs, int* __restrict__ slot,
                       int* __restrict__ esrcp) {
  int e = blockIdx.x*256 + threadIdx.x;
  if (e < N_EDGES) {
    int d = edst[e];
    int p = offs[d] + atomicAdd(&curs[d], 1);
    slot[p] = e;
    esrcp[p] = esrc[e];
  }
}

// ---------------- merged weight fragment prep (f16 single-plane, B-frag order) ----------------
struct PD { const float* W; u16* dst; int Keff, N, KS, nElem; float scale; };
struct PD8 { PD d[8]; int nd; int tot; };

__global__ void k_prepmulti(PD8 ds) {
  int stride = gridDim.x*256;
  for (int t = blockIdx.x*256 + threadIdx.x; t < ds.tot; t += stride) {
    int rem = t, i = 0;
    while (i < ds.nd-1 && rem >= ds.d[i].nElem) { rem -= ds.d[i].nElem; ++i; }
    const PD p = ds.d[i];
    int j = rem & 7;
    int l = (rem >> 3) & 63;
    int rest = rem >> 9;
    int ks = rest % p.KS;
    int nf = rest / p.KS;
    int k   = ks*32 + (l >> 4)*8 + j;
    int col = nf*16 + (l & 15);
    float v = (k < p.Keff) ? p.W[(size_t)k*p.N + col]*p.scale : 0.f;
    p.dst[rem] = f2h(v);
  }
}

// ---------------- fused 3-layer edge MLP via f16 MFMA; 32 edges/wave; packed interleaved out ----------------
// wbuf layout: [p][64 cols][NQ quadrants] u16, NQ = NF3/4 (p = CSR position)
template<int NF3>
__global__ __launch_bounds__(256) void k_mlp(
    const float* __restrict__ es8,
    const u16* __restrict__ fb1, const u16* __restrict__ fb2,
    const u16* __restrict__ fb3, u16* __restrict__ wbuf) {
  __shared__ __align__(16) _Float16 route[4][2304];   // 4 waves x (32 rows x 72 halves)
  const int w = threadIdx.x >> 6, l = threadIdx.x & 63;
  const int lrow = l & 15, lhi = l >> 4;
  const int e0 = (blockIdx.x*4 + w)*32;
  _Float16* rt = route[w];
  constexpr int NQ = NF3/4;

  f16x8 a1[2];
  #pragma unroll
  for (int mt = 0; mt < 2; ++mt) {
    f16x8 z = {0,0,0,0,0,0,0,0};
    if (lhi == 0) z = cvt8(es8 + (size_t)(e0 + mt*16 + lrow)*8);
    a1[mt] = z;
  }

  f32x4 acc1[2][4];
  #pragma unroll
  for (int mt = 0; mt < 2; ++mt)
    #pragma unroll
    for (int nf = 0; nf < 4; ++nf) acc1[mt][nf] = (f32x4){0.f,0.f,0.f,0.f};
  #pragma unroll
  for (int nf = 0; nf < 4; ++nf) {
    f16x8 b = *(const f16x8*)(fb1 + nf*512 + l*8);
    #pragma unroll
    for (int mt = 0; mt < 2; ++mt)
      acc1[mt][nf] = __builtin_amdgcn_mfma_f32_16x16x32_f16(a1[mt], b, acc1[mt][nf], 0,0,0);
  }
  #pragma unroll
  for (int mt = 0; mt < 2; ++mt)
    #pragma unroll
    for (int nf = 0; nf < 4; ++nf)
      #pragma unroll
      for (int r = 0; r < 4; ++r) acc1[mt][nf][r] = siluf(acc1[mt][nf][r]);

  f16x8 a2[2][2];
  #pragma unroll
  for (int mt = 0; mt < 2; ++mt)
    #pragma unroll
    for (int nf = 0; nf < 4; ++nf)
      #pragma unroll
      for (int r = 0; r < 4; ++r)
        rt[(mt*16 + lhi*4 + r)*72 + nf*16 + lrow] = (_Float16)acc1[mt][nf][r];
  #pragma unroll
  for (int mt = 0; mt < 2; ++mt)
    #pragma unroll
    for (int ks = 0; ks < 2; ++ks)
      a2[mt][ks] = *(const f16x8*)&rt[(mt*16 + lrow)*72 + ks*32 + lhi*8];

  f32x4 acc2[2][4];
  #pragma unroll
  for (int mt = 0; mt < 2; ++mt)
    #pragma unroll
    for (int nf = 0; nf < 4; ++nf) acc2[mt][nf] = (f32x4){0.f,0.f,0.f,0.f};
  #pragma unroll
  for (int nf = 0; nf < 4; ++nf)
    #pragma unroll
    for (int ks = 0; ks < 2; ++ks) {
      f16x8 b = *(const f16x8*)(fb2 + (nf*2 + ks)*512 + l*8);
      #pragma unroll
      for (int mt = 0; mt < 2; ++mt)
        acc2[mt][nf] = __builtin_amdgcn_mfma_f32_16x16x32_f16(a2[mt][ks], b, acc2[mt][nf], 0,0,0);
    }
  #pragma unroll
  for (int mt = 0; mt < 2; ++mt)
    #pragma unroll
    for (int nf = 0; nf < 4; ++nf)
      #pragma unroll
      for (int r = 0; r < 4; ++r) acc2[mt][nf][r] = siluf(acc2[mt][nf][r]);

  f16x8 a3[2][2];
  #pragma unroll
  for (int mt = 0; mt < 2; ++mt)
    #pragma unroll
    for (int nf = 0; nf < 4; ++nf)
      #pragma unroll
      for (int r = 0; r < 4; ++r)
        rt[(mt*16 + lhi*4 + r)*72 + nf*16 + lrow] = (_Float16)acc2[mt][nf][r];
  #pragma unroll
  for (int mt = 0; mt < 2; ++mt)
    #pragma unroll
    for (int ks = 0; ks < 2; ++ks)
      a3[mt][ks] = *(const f16x8*)&rt[(mt*16 + lrow)*72 + ks*32 + lhi*8];

  #pragma unroll
  for (int cc = 0; cc < 4; ++cc) {
    f32x4 acc3[NQ][2];
    #pragma unroll
    for (int q = 0; q < NQ; ++q)
      #pragma unroll
      for (int mt = 0; mt < 2; ++mt) acc3[q][mt] = (f32x4){0.f,0.f,0.f,0.f};
    #pragma unroll
    for (int q = 0; q < NQ; ++q) {
      const int nf3 = q*4 + cc;
      #pragma unroll
      for (int ks = 0; ks < 2; ++ks) {
        f16x8 b = *(const f16x8*)(fb3 + ((size_t)nf3*2 + ks)*512 + l*8);
        #pragma unroll
        for (int mt = 0; mt < 2; ++mt)
          acc3[q][mt] = __builtin_amdgcn_mfma_f32_16x16x32_f16(a3[mt][ks], b, acc3[q][mt], 0,0,0);
      }
    }
    const int cbase = (cc*16 + lrow)*NQ;
    #pragma unroll
    for (int mt = 0; mt < 2; ++mt)
      #pragma unroll
      for (int r = 0; r < 4; ++r) {
        const size_t rowoff = (size_t)(e0 + mt*16 + lhi*4 + r)*(NF3*16) + cbase;
        if constexpr (NQ == 4) {
          u16x4 pk;
          #pragma unroll
          for (int q = 0; q < 4; ++q) pk[q] = f2h(acc3[q][mt][r]);
          *(u16x4*)(wbuf + rowoff) = pk;
        } else {
          u16x2 pk;
          #pragma unroll
          for (int q = 0; q < 2; ++q) pk[q] = f2h(acc3[q][mt][r]);
          *(u16x2*)(wbuf + rowoff) = pk;
        }
      }
  }
}

// ---------------- generic f16 MFMA GEMM ----------------
template<int KS, int NF>
__global__ __launch_bounds__(512, 4) void k_gemm(
    const float* __restrict__ A, int rstride, int M,
    const u16* __restrict__ fB, float* __restrict__ O) {
  __shared__ __align__(16) _Float16 lB[NF*KS*512];
  const int tid = threadIdx.x;
  const int w = tid >> 6, l = tid & 63;
  const int lrow = l & 15, lhi = l >> 4;
  const int n0 = blockIdx.x*128 + w*16;
  for (int i = tid; i < NF*KS*64; i += 512)
    *(f16x8*)&lB[(size_t)i*8] = *(const f16x8*)&fB[(size_t)i*8];
  f16x8 a[KS];
  {
    int row = n0 + lrow; if (row > M-1) row = M-1;
    #pragma unroll
    for (int ks = 0; ks < KS; ++ks)
      a[ks] = cvt8(A + (size_t)row*rstride + ks*32 + lhi*8);
  }
  __syncthreads();
  f32x4 acc[NF];
  #pragma unroll
  for (int nf = 0; nf < NF; ++nf) acc[nf] = (f32x4){0.f,0.f,0.f,0.f};
  #pragma unroll
  for (int nf = 0; nf < NF; ++nf)
    #pragma unroll
    for (int ks = 0; ks < KS; ++ks) {
      f16x8 b = *(const f16x8*)&lB[((size_t)(nf*KS + ks))*512 + l*8];
      acc[nf] = __builtin_amdgcn_mfma_f32_16x16x32_f16(a[ks], b, acc[nf], 0,0,0);
    }
  #pragma unroll
  for (int nf = 0; nf < NF; ++nf)
    #pragma unroll
    for (int r = 0; r < 4; ++r) {
      int row = n0 + lhi*4 + r;
      if (row < M) O[(size_t)row*(NF*16) + nf*16 + lrow] = acc[nf][r];
    }
}

// ---------------- sc partial (f16) ----------------
template<int KSO>
__global__ __launch_bounds__(512, 4) void k_scp(
    const float* __restrict__ Ao, const float* __restrict__ na,
    const u16* __restrict__ fBc, float* __restrict__ part) {
  __shared__ __align__(16) _Float16 lB[KSO*4096];
  const int tid = threadIdx.x;
  const int w = tid >> 6, l = tid & 63;
  const int lrow = l & 15, lhi = l >> 4;
  const int n0 = blockIdx.x*128 + w*16;
  const int vp = blockIdx.y;

  f16x8 ao[KSO];
  {
    int row = n0 + lrow; if (row > N_NODES-1) row = N_NODES-1;
    #pragma unroll
    for (int ks = 0; ks < KSO; ++ks)
      ao[ks] = cvt8(Ao + (size_t)row*(KSO*32) + ks*32 + lhi*8);
  }

  f32x4 acc[8];
  #pragma unroll
  for (int nf = 0; nf < 8; ++nf) acc[nf] = (f32x4){0.f,0.f,0.f,0.f};

  #pragma unroll
  for (int c = 0; c < 2; ++c) {
    const int v = vp*2 + c;
    __syncthreads();
    for (int i = tid; i < KSO*512; i += 512) {
      int gl = i & 63;
      int rest = i >> 6;
      int ks = rest % KSO;
      int nf = rest / KSO;
      size_t src = (((size_t)(v*8 + nf)*KSO + ks)*64 + gl)*8;
      *(f16x8*)&lB[(size_t)i*8] = *(const f16x8*)&fBc[src];
    }
    __syncthreads();
    f32x4 dacc[8];
    #pragma unroll
    for (int nf = 0; nf < 8; ++nf) dacc[nf] = (f32x4){0.f,0.f,0.f,0.f};
    #pragma unroll
    for (int nf = 0; nf < 8; ++nf)
      #pragma unroll
      for (int ks = 0; ks < KSO; ++ks) {
        f16x8 b = *(const f16x8*)&lB[((size_t)(nf*KSO + ks))*512 + l*8];
        dacc[nf] = __builtin_amdgcn_mfma_f32_16x16x32_f16(ao[ks], b, dacc[nf], 0,0,0);
      }
    #pragma unroll
    for (int r = 0; r < 4; ++r) {
      int row = n0 + lhi*4 + r; if (row > N_NODES-1) row = N_NODES-1;
      float nav = na[(size_t)row*16 + v];
      #pragma unroll
      for (int nf = 0; nf < 8; ++nf) acc[nf][r] += nav * dacc[nf][r];
    }
  }

  float* pp = part + (size_t)vp*NM128;
  #pragma unroll
  for (int nf = 0; nf < 8; ++nf)
    #pragma unroll
    for (int r = 0; r < 4; ++r) {
      int row = n0 + lhi*4 + r;
      if (row < N_NODES) pp[(size_t)row*128 + nf*16 + lrow] = acc[nf][r];
    }
}

// ---------------- fused reduce(9) + gating ----------------
__global__ void k_redgate(const float* __restrict__ part, const float* __restrict__ ov,
                          float* __restrict__ gs_out, float* __restrict__ gv) {
  int t = blockIdx.x*256 + threadIdx.x;
  if (t >= N_NODES*64) return;
  int n = t >> 6, v = t & 63;
  float o1 = 0.f, o2 = 0.f;
  #pragma unroll
  for (int p = 0; p < 9; ++p) {
    const float* pp = part + (size_t)p*NM128 + (size_t)n*128;
    o1 += pp[v]; o2 += pp[64+v];
  }
  float g = siluf(o1), gate = sigf(o2);
  gs_out[(size_t)n*64+v] = g;
  gv[(size_t)n*192 + 0*64 + v] = gate*ov[(size_t)n*192 + 0*64 + v];
  gv[(size_t)n*192 + 1*64 + v] = gate*ov[(size_t)n*192 + 1*64 + v];
  gv[(size_t)n*192 + 2*64 + v] = gate*ov[(size_t)n*192 + 2*64 + v];
}

// ---------------- fused reduce(9) + pooled accumulation (RLE) ----------------
__global__ __launch_bounds__(128) void k_redpool(
    const float* __restrict__ part, const int* __restrict__ batch,
    float* __restrict__ pool) {
  const int j = threadIdx.x;
  const int n0 = blockIdx.x*4;
  float outv[4];
  #pragma unroll
  for (int nn = 0; nn < 4; ++nn) {
    float sv = 0.f;
    #pragma unroll
    for (int p = 0; p < 9; ++p)
      sv += part[(size_t)p*NM128 + (size_t)(n0+nn)*128 + j];
    outv[nn] = sv;
  }
  int b0 = batch[n0], b1 = batch[n0+1], b2 = batch[n0+2], b3 = batch[n0+3];
  float sum = outv[0]; int cur = b0;
  if (b1 == cur) sum += outv[1]; else { atomicAdd(&pool[cur*128+j], sum); cur = b1; sum = outv[1]; }
  if (b2 == cur) sum += outv[2]; else { atomicAdd(&pool[cur*128+j], sum); cur = b2; sum = outv[2]; }
  if (b3 == cur) sum += outv[3]; else { atomicAdd(&pool[cur*128+j], sum); cur = b3; sum = outv[3]; }
  atomicAdd(&pool[cur*128+j], sum);
}

// ---------------- conv1 gather: sequential CSR stream (wbuf/shv/esrcp in CSR order) ----------------
__global__ __launch_bounds__(256) void k_gather1(
    const u16* __restrict__ wbuf, const float* __restrict__ shv,
    const int* __restrict__ esrcp, const int* __restrict__ offs,
    const float* __restrict__ h,
    float* __restrict__ n_s, float* __restrict__ n_v) {
  const int wave = threadIdx.x >> 6, lane = threadIdx.x & 63;
  const int n = blockIdx.x*4 + wave;
  if (n >= N_NODES) return;
  const int s0 = offs[n], s1 = offs[n+1];
  float ns0=0.f, ns1=0.f;
  float nv00=0.f,nv01=0.f,nv02=0.f, nv10=0.f,nv11=0.f,nv12=0.f;
  for (int s = s0; s < s1; ++s) {
    int src = esrcp[s];
    u16x4 wv = *(const u16x4*)(wbuf + (size_t)s*256 + lane*4);
    float c0 = h2f(wv[0]), c1 = h2f(wv[1]), c2 = h2f(wv[2]), c3 = h2f(wv[3]);
    float h0 = h[src*128+lane], h1 = h[src*128+64+lane];
    float sv0 = shv[(size_t)s*3+0], sv1 = shv[(size_t)s*3+1], sv2 = shv[(size_t)s*3+2];
    ns0 += c0*h0; ns1 += c1*h1;
    float t0 = c2*h0, t1 = c3*h1;
    nv00 += t0*sv0; nv01 += t0*sv1; nv02 += t0*sv2;
    nv10 += t1*sv0; nv11 += t1*sv1; nv12 += t1*sv2;
  }
  n_s[n*128+lane]    = ns0*INV_SQRT10;
  n_s[n*128+64+lane] = ns1*INV_SQRT10;
  float* nvp = n_v + (size_t)n*384;      // [3][128]
  nvp[0*128+lane]    = nv00*INV_SQRT10;
  nvp[1*128+lane]    = nv01*INV_SQRT10;
  nvp[2*128+lane]    = nv02*INV_SQRT10;
  nvp[0*128+64+lane] = nv10*INV_SQRT10;
  nvp[1*128+64+lane] = nv11*INV_SQRT10;
  nvp[2*128+64+lane] = nv12*INV_SQRT10;
}

// ---------------- conv2 gather: sequential CSR stream; h_v layout [n][3][64] ----------------
__global__ __launch_bounds__(256) void k_gather2(
    const u16* __restrict__ wbuf, const float* __restrict__ shv,
    const int* __restrict__ esrcp, const int* __restrict__ offs,
    const float* __restrict__ h_s, const float* __restrict__ h_v,
    float* __restrict__ n_mid) {
  const int wave = threadIdx.x >> 6, lane = threadIdx.x & 63;
  const int n = blockIdx.x*4 + wave;
  if (n >= N_NODES) return;
  const int s0 = offs[n], s1 = offs[n+1];
  float acc0 = 0.f, acc1 = 0.f;
  for (int s = s0; s < s1; ++s) {
    int src = esrcp[s];
    u16x2 wv = *(const u16x2*)(wbuf + (size_t)s*128 + lane*2);
    float w0 = h2f(wv[0]), w1 = h2f(wv[1]);
    float hs = h_s[src*64+lane];
    const float* hvp = h_v + (size_t)src*192;
    float sv0 = shv[(size_t)s*3+0], sv1 = shv[(size_t)s*3+1], sv2 = shv[(size_t)s*3+2];
    float dot = hvp[lane]*sv0 + hvp[64+lane]*sv1 + hvp[128+lane]*sv2;
    acc0 += w0*hs;
    acc1 += w1*dot;
  }
  n_mid[n*128+lane]    = acc0*INV_SQRT10;
  n_mid[n*128+64+lane] = acc1*INV_SQRT3*INV_SQRT10;
}

// ======== FALLBACK (atomic) kernels — used only if ws too small ========
__global__ __launch_bounds__(512) void k_edge1_at(
    const float* __restrict__ es8, const float* __restrict__ shv,
    const int* __restrict__ esrc, const int* __restrict__ edst,
    const float* __restrict__ h,
    const float* __restrict__ W0, const float* __restrict__ W1, const float* __restrict__ W2,
    float* __restrict__ n_s, float* __restrict__ n_v) {
  __shared__ float lW0[512];
  __shared__ float lW1[4096];
  __shared__ float lW2[16384];
  __shared__ float lA[8][64];
  __shared__ float lB[8][64];
  for (int i = threadIdx.x; i < 512;   i += 512) lW0[i] = W0[i];
  for (int i = threadIdx.x; i < 4096;  i += 512) lW1[i] = W1[i];
  for (int i = threadIdx.x; i < 16384; i += 512) lW2[i] = W2[i];
  __syncthreads();
  const int wave = threadIdx.x >> 6, lane = threadIdx.x & 63;
  const int nw = gridDim.x * 8;
  const int e0 = blockIdx.x*8 + wave;
  const int iters = (N_EDGES + nw - 1) / nw;
  for (int it = 0; it < iters; ++it) {
    int e = e0 + it*nw;
    bool valid = e < N_EDGES;
    float a = 0.f, sv0=0.f, sv1=0.f, sv2=0.f;
    int src = 0, dst = 0;
    if (valid) {
      const float* ep = es8 + e*8;
      sv0 = shv[e*3+0]; sv1 = shv[e*3+1]; sv2 = shv[e*3+2];
      src = esrc[e]; dst = edst[e];
      a = ep[0]*lW0[lane]      + ep[1]*lW0[64+lane]  + ep[2]*lW0[128+lane] + ep[3]*lW0[192+lane]
        + ep[4]*lW0[256+lane]  + ep[5]*lW0[320+lane] + ep[6]*lW0[384+lane] + ep[7]*lW0[448+lane];
      a = siluf(a * INV_SQRT8);
    }
    lA[wave][lane] = a;
    __syncthreads();
    {
      float b0=0.f;
      #pragma unroll
      for (int k = 0; k < 64; ++k) b0 += lA[wave][k]*lW1[k*64+lane];
      lB[wave][lane] = siluf(b0 * INV_SQRT64);
    }
    __syncthreads();
    if (valid) {
      float c0=0.f,c1=0.f,c2=0.f,c3=0.f;
      #pragma unroll
      for (int k = 0; k < 64; ++k) {
        float bk = lB[wave][k];
        const float* r = lW2 + k*256;
        c0 += bk*r[lane]; c1 += bk*r[64+lane]; c2 += bk*r[128+lane]; c3 += bk*r[192+lane];
      }
      float hs0 = h[src*128 + lane];
      float hs1 = h[src*128 + 64 + lane];
      atomicAdd(&n_s[dst*128 + lane],      c0*INV_SQRT64*hs0*INV_SQRT10);
      atomicAdd(&n_s[dst*128 + 64 + lane], c1*INV_SQRT64*hs1*INV_SQRT10);
      float t0 = c2*INV_SQRT64*hs0*INV_SQRT10;
      float t1 = c3*INV_SQRT64*hs1*INV_SQRT10;
      float* nvp = n_v + dst*384;
      atomicAdd(nvp + lane*3+0, t0*sv0);
      atomicAdd(nvp + lane*3+1, t0*sv1);
      atomicAdd(nvp + lane*3+2, t0*sv2);
      atomicAdd(nvp + (64+lane)*3+0, t1*sv0);
      atomicAdd(nvp + (64+lane)*3+1, t1*sv1);
      atomicAdd(nvp + (64+lane)*3+2, t1*sv2);
    }
  }
}

__global__ __launch_bounds__(512) void k_edge2_at(
    const float* __restrict__ es8, const float* __restrict__ shv,
    const int* __restrict__ esrc, const int* __restrict__ edst,
    const float* __restrict__ h_s, const float* __restrict__ h_v,
    const float* __restrict__ W0, const float* __restrict__ W1, const float* __restrict__ W2,
    float* __restrict__ n_mid) {
  __shared__ float lW0[512];
  __shared__ float lW1[4096];
  __shared__ float lW2[8192];
  __shared__ float lA[8][64];
  __shared__ float lB[8][64];
  for (int i = threadIdx.x; i < 512;  i += 512) lW0[i] = W0[i];
  for (int i = threadIdx.x; i < 4096; i += 512) lW1[i] = W1[i];
  for (int i = threadIdx.x; i < 8192; i += 512) lW2[i] = W2[i];
  __syncthreads();
  const int wave = threadIdx.x >> 6, lane = threadIdx.x & 63;
  const int nw = gridDim.x * 8;
  const int e0 = blockIdx.x*8 + wave;
  const int iters = (N_EDGES + nw - 1) / nw;
  for (int it = 0; it < iters; ++it) {
    int e = e0 + it*nw;
    bool valid = e < N_EDGES;
    float a = 0.f, sv0=0.f, sv1=0.f, sv2=0.f;
    int src = 0, dst = 0;
    if (valid) {
      const float* ep = es8 + e*8;
      sv0 = shv[e*3+0]; sv1 = shv[e*3+1]; sv2 = shv[e*3+2];
      src = esrc[e]; dst = edst[e];
      a = ep[0]*lW0[lane]      + ep[1]*lW0[64+lane]  + ep[2]*lW0[128+lane] + ep[3]*lW0[192+lane]
        + ep[4]*lW0[256+lane]  + ep[5]*lW0[320+lane] + ep[6]*lW0[384+lane] + ep[7]*lW0[448+lane];
      a = siluf(a * INV_SQRT8);
    }
    lA[wave][lane] = a;
    __syncthreads();
    {
      float b0=0.f;
      #pragma unroll
      for (int k = 0; k < 64; ++k) b0 += lA[wave][k]*lW1[k*64+lane];
      lB[wave][lane] = siluf(b0 * INV_SQRT64);
    }
    __syncthreads();
    if (valid) {
      float c0=0.f, c1=0.f;
      #pragma unroll
      for (int k = 0; k < 64; ++k) {
        float bk = lB[wave][k];
        const float* r = lW2 + k*128;
        c0 += bk*r[lane]; c1 += bk*r[64+lane];
      }
      float hsv = h_s[src*64 + lane];
      const float* hvp = h_v + src*192 + lane*3;
      float dotv = hvp[0]*sv0 + hvp[1]*sv1 + hvp[2]*sv2;
      atomicAdd(&n_mid[dst*128 + lane],      c0*INV_SQRT64*hsv*INV_SQRT10);
      atomicAdd(&n_mid[dst*128 + 64 + lane], c1*INV_SQRT64*dotv*INV_SQRT3*INV_SQRT10);
    }
  }
}

// ---------------- FALLBACK conv1 node pass (full, old n_v layout) ----------------
__global__ __launch_bounds__(128) void k_node1(
    const float* __restrict__ n_s, const float* __restrict__ n_v,
    const float* __restrict__ s,   const float* __restrict__ na,
    const float* __restrict__ Wls, const float* __restrict__ Wlv,
    const float* __restrict__ Csc, const float* __restrict__ W2s, const float* __restrict__ W2v,
    float* __restrict__ gs_out, float* __restrict__ hs_out, float* __restrict__ hv_out) {
  __shared__ float l_ns[512], l_s[512], l_na[64], l_nv[1536];
  __shared__ float l_outs[512], l_ov[768], l_gs[256], l_gv[768];
  const int j = threadIdx.x;
  const int n0 = blockIdx.x*4;
  for (int i = j; i < 512;  i += 128) { l_ns[i] = n_s[n0*128+i]; l_s[i] = s[n0*128+i]; }
  for (int i = j; i < 1536; i += 128) l_nv[i] = n_v[n0*384+i];
  if (j < 64) l_na[j] = na[n0*16+j];
  __syncthreads();

  float accs[4] = {0.f,0.f,0.f,0.f};
  for (int k = 0; k < 128; ++k) {
    float w = Wls[k*128+j];
    accs[0] += l_ns[k]*w; accs[1] += l_ns[128+k]*w;
    accs[2] += l_ns[256+k]*w; accs[3] += l_ns[384+k]*w;
  }
  float accc[4] = {0.f,0.f,0.f,0.f};
  for (int vt = 0; vt < 16; vt += 4) {
    float a0[4],a1[4],a2[4],a3[4];
    #pragma unroll
    for (int n = 0; n < 4; ++n) {
      a0[n]=l_na[n*16+vt]; a1[n]=l_na[n*16+vt+1];
      a2[n]=l_na[n*16+vt+2]; a3[n]=l_na[n*16+vt+3];
    }
    for (int u = 0; u < 128; ++u) {
      const float* cp = Csc + (u*16+vt)*128 + j;
      float c0=cp[0], c1=cp[128], c2=cp[256], c3=cp[384];
      float s0=l_s[u], s1=l_s[128+u], s2=l_s[256+u], s3=l_s[384+u];
      accc[0] += s0*(a0[0]*c0 + a1[0]*c1 + a2[0]*c2 + a3[0]*c3);
      accc[1] += s1*(a0[1]*c0 + a1[1]*c1 + a2[1]*c2 + a3[1]*c3);
      accc[2] += s2*(a0[2]*c0 + a1[2]*c1 + a2[2]*c2 + a3[2]*c3);
      accc[3] += s3*(a0[3]*c0 + a1[3]*c1 + a2[3]*c2 + a3[3]*c3);
    }
  }
  #pragma unroll
  for (int n = 0; n < 4; ++n)
    l_outs[n*128+j] = accs[n]*INV_SQRT128 + accc[n]*INV_SQRT2048;

  const int jj = j & 63, hh = j >> 6;
  float ov[2][3] = {{0.f,0.f,0.f},{0.f,0.f,0.f}};
  for (int u = 0; u < 128; ++u) {
    float w = Wlv[u*64+jj];
    #pragma unroll
    for (int t = 0; t < 2; ++t) {
      int n = 2*hh+t;
      ov[t][0] += l_nv[n*384+u*3+0]*w;
      ov[t][1] += l_nv[n*384+u*3+1]*w;
      ov[t][2] += l_nv[n*384+u*3+2]*w;
    }
  }
  #pragma unroll
  for (int t = 0; t < 2; ++t) {
    int n = 2*hh+t;
    l_ov[n*192+jj*3+0] = ov[t][0]*INV_SQRT128;
    l_ov[n*192+jj*3+1] = ov[t][1]*INV_SQRT128;
    l_ov[n*192+jj*3+2] = ov[t][2]*INV_SQRT128;
  }
  __syncthreads();

  #pragma unroll
  for (int t = 0; t < 2; ++t) {
    int n = 2*hh+t;
    float gv_s = siluf(l_outs[n*128+jj]);
    float gate = sigf (l_outs[n*128+64+jj]);
    l_gs[n*64+jj] = gv_s;
    gs_out[(n0+n)*64+jj] = gv_s;
    l_gv[n*192+jj*3+0] = gate*l_ov[n*192+jj*3+0];
    l_gv[n*192+jj*3+1] = gate*l_ov[n*192+jj*3+1];
    l_gv[n*192+jj*3+2] = gate*l_ov[n*192+jj*3+2];
  }
  __syncthreads();

  float ha[2] = {0.f,0.f};
  for (int k = 0; k < 64; ++k) {
    float w = W2s[k*64+jj];
    ha[0] += l_gs[(2*hh+0)*64+k]*w;
    ha[1] += l_gs[(2*hh+1)*64+k]*w;
  }
  hs_out[(n0+2*hh+0)*64+jj] = ha[0]*INV_SQRT64;
  hs_out[(n0+2*hh+1)*64+jj] = ha[1]*INV_SQRT64;

  float hv[2][3] = {{0.f,0.f,0.f},{0.f,0.f,0.f}};
  for (int u = 0; u < 64; ++u) {
    float w = W2v[u*64+jj];
    #pragma unroll
    for (int t = 0; t < 2; ++t) {
      int n = 2*hh+t;
      hv[t][0] += l_gv[n*192+u*3+0]*w;
      hv[t][1] += l_gv[n*192+u*3+1]*w;
      hv[t][2] += l_gv[n*192+u*3+2]*w;
    }
  }
  #pragma unroll
  for (int t = 0; t < 2; ++t) {
    int n = 2*hh+t;
    hv_out[(n0+n)*192+jj*3+0] = hv[t][0]*INV_SQRT64;
    hv_out[(n0+n)*192+jj*3+1] = hv[t][1]*INV_SQRT64;
    hv_out[(n0+n)*192+jj*3+2] = hv[t][2]*INV_SQRT64;
  }
}

// ---------------- FALLBACK conv2 node pass + pooling ----------------
__global__ __launch_bounds__(128) void k_node2(
    const float* __restrict__ n_mid, const float* __restrict__ gs,
    const float* __restrict__ na, const int* __restrict__ batch,
    const float* __restrict__ W, const float* __restrict__ Csc,
    float* __restrict__ pool) {
  __shared__ float l_nm[512], l_gs[256], l_na[64];
  const int j = threadIdx.x;
  const int n0 = blockIdx.x*4;
  for (int i = j; i < 512; i += 128) l_nm[i] = n_mid[n0*128+i];
  for (int i = j; i < 256; i += 128) l_gs[i] = gs[n0*64+i];
  if (j < 64) l_na[j] = na[n0*16+j];
  __syncthreads();
  float acc[4] = {0.f,0.f,0.f,0.f};
  for (int k = 0; k < 128; ++k) {
    float w = W[k*128+j];
    acc[0] += l_nm[k]*w; acc[1] += l_nm[128+k]*w;
    acc[2] += l_nm[256+k]*w; acc[3] += l_nm[384+k]*w;
  }
  float acc2[4] = {0.f,0.f,0.f,0.f};
  for (int vt = 0; vt < 16; vt += 4) {
    float a0[4],a1[4],a2[4],a3[4];
    #pragma unroll
    for (int n = 0; n < 4; ++n) {
      a0[n]=l_na[n*16+vt]; a1[n]=l_na[n*16+vt+1];
      a2[n]=l_na[n*16+vt+2]; a3[n]=l_na[n*16+vt+3];
    }
    for (int u = 0; u < 64; ++u) {
      const float* cp = Csc + (u*16+vt)*128 + j;
      float c0=cp[0], c1=cp[128], c2=cp[256], c3=cp[384];
      float s0=l_gs[u], s1=l_gs[64+u], s2=l_gs[128+u], s3=l_gs[192+u];
      acc2[0] += s0*(a0[0]*c0 + a1[0]*c1 + a2[0]*c2 + a3[0]*c3);
      acc2[1] += s1*(a0[1]*c0 + a1[1]*c1 + a2[1]*c2 + a3[1]*c3);
      acc2[2] += s2*(a0[2]*c0 + a1[2]*c1 + a2[2]*c2 + a3[2]*c3);
      acc2[3] += s3*(a0[3]*c0 + a1[3]*c1 + a2[3]*c2 + a3[3]*c3);
    }
  }
  float outv[4];
  #pragma unroll
  for (int n = 0; n < 4; ++n)
    outv[n] = acc[n]*INV_SQRT128 + acc2[n]*INV_SQRT1024;
  int b0 = batch[n0], b1 = batch[n0+1], b2 = batch[n0+2], b3 = batch[n0+3];
  float sum = outv[0]; int cur = b0;
  if (b1 == cur) sum += outv[1]; else { atomicAdd(&pool[cur*128+j], sum); cur = b1; sum = outv[1]; }
  if (b2 == cur) sum += outv[2]; else { atomicAdd(&pool[cur*128+j], sum); cur = b2; sum = outv[2]; }
  if (b3 == cur) sum += outv[3]; else { atomicAdd(&pool[cur*128+j], sum); cur = b3; sum = outv[3]; }
  atomicAdd(&pool[cur*128+j], sum);
}

// ---------------- readout head ----------------
__global__ __launch_bounds__(128) void k_head(
    const float* __restrict__ pool, const float* __restrict__ cnt,
    const float* __restrict__ Wr1, const float* __restrict__ Wr2,
    float* __restrict__ out) {
  __shared__ float lp[128];
  __shared__ float lt[128];
  const int j = threadIdx.x;
  for (int g = 0; g < N_GRAPHS; ++g) {
    float inv = 1.f / fmaxf(cnt[g], 1.f);
    lp[j] = pool[g*128+j]*inv;
    __syncthreads();
    float acc = 0.f;
    for (int k = 0; k < 128; ++k) acc += lp[k]*Wr1[k*128+j];
    lt[j] = siluf(acc*INV_SQRT128) * Wr2[j];
    __syncthreads();
    if (j == 0) {
      float ssum = 0.f;
      for (int k = 0; k < 128; ++k) ssum += lt[k];
      out[g] = ssum*INV_SQRT128;
    }
    __syncthreads();
  }
}

extern "C" void kernel_launch(void* const* d_in, const int* in_sizes, int n_in,
                              void* d_out, int out_size, void* d_ws, size_t ws_size,
                              hipStream_t stream) {
  const float* x         = (const float*)d_in[0];
  const float* node_attr = (const float*)d_in[1];
  const int*   esrc      = (const int*)d_in[2];
  const int*   edst      = (const int*)d_in[3];
  const float* evec      = (const float*)d_in[4];
  const int*   batch     = (const int*)d_in[5];
  const float* W_embed   = (const float*)d_in[6];
  const float* c1_lin1   = (const float*)d_in[7];
  const float* c1_fc_w0  = (const float*)d_in[8];
  const float* c1_fc_w1  = (const float*)d_in[9];
  const float* c1_fc_w2  = (const float*)d_in[10];
  const float* c1_lin2_s = (const float*)d_in[11];
  const float* c1_lin2_v = (const float*)d_in[12];
  const float* c1_sc     = (const float*)d_in[13];
  const float* c2_lin1_s = (const float*)d_in[14];
  const float* c2_lin1_v = (const float*)d_in[15];
  const float* c2_fc_w0  = (const float*)d_in[16];
  const float* c2_fc_w1  = (const float*)d_in[17];
  const float* c2_fc_w2  = (const float*)d_in[18];
  const float* c2_lin2   = (const float*)d_in[19];
  const float* c2_sc     = (const float*)d_in[20];
  const float* Wr1       = (const float*)d_in[21];
  const float* Wr2       = (const float*)d_in[22];

  float* ws    = (float*)d_ws;
  float* es8   = ws + OFF_ES8;
  float* shv   = ws + OFF_SHV;
  float* s_    = ws + OFF_S;
  float* h_    = ws + OFF_H;
  float* gs_   = ws + OFF_GS;
  float* hs_   = ws + OFF_HS;
  float* hv_   = ws + OFF_HV;
  float* ns_   = ws + OFF_NS;
  float* nv_   = ws + OFF_NV;
  float* nmid_ = ws + OFF_NMID;
  float* pool_ = ws + OFF_POOL;
  float* cnt_  = ws + OFF_CNT;
  int*   hist_ = (int*)(ws + OFF_HIST);
  int*   curs_ = (int*)(ws + OFF_CURS);
  int*   offs_ = (int*)(ws + OFF_OFFS);
  u16*   frag_ = (u16*)(ws + OFF_FRAG);
  int*   slot_ = (int*)(ws + OFF_SLOT);
  float* wbuf_ = ws + OFF_WBUF;
  u16*   wb16_ = (u16*)wbuf_;   // fp16 wbuf occupies only lower half of WBUF region

  // upper-wbuf carve-outs
  float* out1_  = wbuf_ + (size_t)N_EDGES*128;                 // reserved (layout stability)
  u16*   nfrag_ = (u16*)(out1_ + (size_t)NM128);               // 442368 u16
  float* part_  = out1_ + (size_t)NM128 + NFRAG_TOT/2;         // 9 x 1.28M floats
  float* ov_    = part_ + (size_t)9*NM128;                     // 1.92M floats
  int*   esrcp_ = (int*)(ov_ + (size_t)N_NODES*192);           // N_EDGES ints
  float* gv_    = nv_;                                         // aliases nv (dead after ov GEMM)

  const bool big = ws_size >= WS_NEED_BYTES;

  if (big) {
    hipMemsetAsync(pool_, 0, (size_t)(OFF_OFFS - OFF_POOL)*sizeof(float), stream);
    k_cnthist<<<(N_EDGES+255)/256, 256, 0, stream>>>(batch, edst, cnt_, hist_);
    k_scanp<<<1, 1024, 0, stream>>>(hist_, offs_);
    k_slot<<<(N_EDGES+255)/256, 256, 0, stream>>>(edst, esrc, offs_, curs_, slot_, esrcp_);
    // edge geometry in CSR order
    k_geom_csr<<<(N_EDGES+255)/256, 256, 0, stream>>>(evec, slot_, es8, shv);

    // merged startup frag prep: 6 MLP weights + W_embed + c1_lin1 (f16 single-plane)
    {
      PD8 m{};
      m.d[0] = {c1_fc_w0, frag_ + F_B1,  8,  64,  1, 2048,  INV_SQRT8};
      m.d[1] = {c1_fc_w1, frag_ + F_B2,  64, 64,  2, 4096,  INV_SQRT64};
      m.d[2] = {c1_fc_w2, frag_ + F_B3,  64, 256, 2, 16384, INV_SQRT64};
      m.d[3] = {c2_fc_w0, frag_ + F_B1b, 8,  64,  1, 2048,  INV_SQRT8};
      m.d[4] = {c2_fc_w1, frag_ + F_B2b, 64, 64,  2, 4096,  INV_SQRT64};
      m.d[5] = {c2_fc_w2, frag_ + F_B3b, 64, 128, 2, 8192,  INV_SQRT64};
      m.d[6] = {W_embed,  frag_ + F_WE,  32, 128, 1, 4096,  INV_SQRT32};
      m.d[7] = {c1_lin1,  frag_ + F_L1,  128,128, 4, 16384, INV_SQRT128};
      m.nd = 8; m.tot = FRAG_TOT;
      k_prepmulti<<<224, 256, 0, stream>>>(m);
    }

    // s = x@W_embed ; h = s@c1_lin1 (f16 MFMA)
    k_gemm<1,8><<<79, 512, 0, stream>>>(x,  32,  N_NODES, frag_ + F_WE, s_);
    k_gemm<4,8><<<79, 512, 0, stream>>>(s_, 128, N_NODES, frag_ + F_L1, h_);

    // conv1 edge MLP (CSR-ordered) + streaming gather
    k_mlp<16><<<1250, 256, 0, stream>>>(es8, frag_ + F_B1, frag_ + F_B2, frag_ + F_B3, wb16_);
    k_gather1<<<(N_NODES+3)/4, 256, 0, stream>>>(wb16_, shv, esrcp_, offs_, h_, ns_, nv_);

    // merged node weight frag prep (f16 single-plane)
    {
      PD8 m{};
      m.d[0] = {c1_lin2_s, nfrag_ + NF_WLS, 128, 128,  4, 16384,  INV_SQRT128};
      m.d[1] = {c1_sc,     nfrag_ + NF_C1,  128, 2048, 4, 262144, INV_SQRT2048};
      m.d[2] = {c2_lin2,   nfrag_ + NF_W2,  128, 128,  4, 16384,  INV_SQRT128};
      m.d[3] = {c2_sc,     nfrag_ + NF_C2,  64,  2048, 2, 131072, INV_SQRT1024};
      m.d[4] = {c1_lin2_v, nfrag_ + NF_LV,  128, 64,   4, 8192,   INV_SQRT128};
      m.d[5] = {c2_lin1_s, nfrag_ + NF_2S,  64,  64,   2, 4096,   INV_SQRT64};
      m.d[6] = {c2_lin1_v, nfrag_ + NF_2V,  64,  64,   2, 4096,   INV_SQRT64};
      m.nd = 7; m.tot = NFRAG_TOT;
      k_prepmulti<<<864, 256, 0, stream>>>(m);
    }

    // conv1 node: dense + sc partials -> fused reduce+gate
    k_gemm<4,8><<<79, 512, 0, stream>>>(ns_, 128, N_NODES, nfrag_ + NF_WLS, part_ + (size_t)8*NM128);
    k_scp<4><<<dim3(79,8), 512, 0, stream>>>(s_, node_attr, nfrag_ + NF_C1, part_);
    k_gemm<4,4><<<235, 512, 0, stream>>>(nv_, 128, N_NODES*3, nfrag_ + NF_LV, ov_);
    k_redgate<<<(N_NODES*64+255)/256, 256, 0, stream>>>(part_, ov_, gs_, gv_);
    k_gemm<2,4><<<79, 512, 0, stream>>>(gs_, 64, N_NODES, nfrag_ + NF_2S, hs_);
    k_gemm<2,4><<<235, 512, 0, stream>>>(gv_, 64, N_NODES*3, nfrag_ + NF_2V, hv_);

    // conv2 edge MLP + streaming gather
    k_mlp<8><<<1250, 256, 0, stream>>>(es8, frag_ + F_B1b, frag_ + F_B2b, frag_ + F_B3b, wb16_);
    k_gather2<<<(N_NODES+3)/4, 256, 0, stream>>>(wb16_, shv, esrcp_, offs_, hs_, hv_, nmid_);

    // conv2 node: partials -> fused reduce+pool
    k_gemm<4,8><<<79, 512, 0, stream>>>(nmid_, 128, N_NODES, nfrag_ + NF_W2, part_ + (size_t)8*NM128);
    k_scp<2><<<dim3(79,8), 512, 0, stream>>>(gs_, node_attr, nfrag_ + NF_C2, part_);
    k_redpool<<<N_NODES/4, 128, 0, stream>>>(part_, batch, pool_);
  } else {
    hipMemsetAsync(ns_, 0, (size_t)(OFF_HIST - OFF_NS)*sizeof(float), stream);
    k_geom_id<<<N_EDGES/256, 256, 0, stream>>>(evec, es8, shv);
    k_linear128<<<(N_NODES*128)/256, 256, 0, stream>>>(x,  W_embed, s_, 32,  INV_SQRT32,  N_NODES*128);
    k_linear128<<<(N_NODES*128)/256, 256, 0, stream>>>(s_, c1_lin1, h_, 128, INV_SQRT128, N_NODES*128);
    k_cnthist<<<(N_EDGES+255)/256, 256, 0, stream>>>(batch, edst, cnt_, hist_);
    k_edge1_at<<<256, 512, 0, stream>>>(es8, shv, esrc, edst, h_,
                                        c1_fc_w0, c1_fc_w1, c1_fc_w2, ns_, nv_);
    k_node1<<<N_NODES/4, 128, 0, stream>>>(ns_, nv_, s_, node_attr,
                                           c1_lin2_s, c1_lin2_v, c1_sc,
                                           c2_lin1_s, c2_lin1_v, gs_, hs_, hv_);
    k_edge2_at<<<512, 512, 0, stream>>>(es8, shv, esrc, edst, hs_, hv_,
                                        c2_fc_w0, c2_fc_w1, c2_fc_w2, nmid_);
    k_node2<<<N_NODES/4, 128, 0, stream>>>(nmid_, gs_, node_attr, batch,
                                           c2_lin2, c2_sc, pool_);
  }

  k_head<<<1, 128, 0, stream>>>(pool_, cnt_, Wr1, Wr2, (float*)d_out);
}

// Round 12
// 275.442 us; speedup vs baseline: 4.5567x; 1.1214x over previous
//
#include <hip/hip_runtime.h>
#include <hip/hip_fp16.h>

#define N_NODES 10000
#define N_EDGES 160000
#define N_GRAPHS 16

typedef __attribute__((ext_vector_type(8))) _Float16 f16x8;
typedef __attribute__((ext_vector_type(4))) float f32x4;
typedef __attribute__((ext_vector_type(4))) unsigned short u16x4;
typedef __attribute__((ext_vector_type(2))) unsigned short u16x2;
typedef unsigned int uint32;
typedef unsigned short u16;

// ---- workspace layout (float offsets) ----
#define OFF_ES8  0
#define OFF_SHV  (OFF_ES8 + N_EDGES*8)
#define OFF_S    (OFF_SHV + N_EDGES*3)
#define OFF_H    (OFF_S   + N_NODES*128)
#define OFF_GS   (OFF_H   + N_NODES*128)
#define OFF_HS   (OFF_GS  + N_NODES*64)
#define OFF_HV   (OFF_HS  + N_NODES*64)
#define OFF_NS   (OFF_HV  + N_NODES*192)   /* fallback zero-region start */
#define OFF_NV   (OFF_NS  + N_NODES*128)
#define OFF_NMID (OFF_NV  + N_NODES*384)
#define OFF_POOL (OFF_NMID+ N_NODES*128)   /* new-path zero-region start */
#define OFF_CNT  (OFF_POOL+ N_GRAPHS*128)
#define OFF_HIST (OFF_CNT + N_GRAPHS)
#define OFF_CURS (OFF_HIST+ N_NODES)
#define OFF_OFFS (OFF_CURS+ N_NODES)       /* new-path zero-region end (excl) */
#define OFF_FRAG (OFF_OFFS+ N_NODES + 16)  /* persistent frags: 57344 u16 (f16 single-plane) */
#define OFF_SLOT (OFF_FRAG+ 57344)
#define OFF_WBUF (OFF_SLOT+ N_EDGES)
#define WBUF_FLOATS ((size_t)N_EDGES*256)
#define WS_NEED_BYTES ((size_t)(OFF_WBUF + WBUF_FLOATS) * 4)

// persistent frag sub-offsets in u16 (single-plane f16: NF*KS*512 each)
#define F_B1   0        /* conv1 L1: NF4 KS1 -> 2048  */
#define F_B2   2048     /* conv1 L2: NF4 KS2 -> 4096  */
#define F_B3   6144     /* conv1 L3: NF16 KS2 -> 16384 */
#define F_B1b  22528
#define F_B2b  24576
#define F_B3b  28672    /* conv2 L3: NF8 KS2 -> 8192 */
#define F_WE   36864    /* W_embed: NF8 KS1 -> 4096 */
#define F_L1   40960    /* c1_lin1: NF8 KS4 -> 16384 */
#define FRAG_TOT 57344

// node-frag sub-offsets in u16
#define NF_WLS 0        /* c1_lin2_s: NF8 KS4 -> 16384 */
#define NF_C1  16384    /* c1_sc:   NF128 KS4 -> 262144 */
#define NF_W2  278528   /* c2_lin2:  NF8 KS4 -> 16384 */
#define NF_C2  294912   /* c2_sc:   NF128 KS2 -> 131072 */
#define NF_LV  425984   /* c1_lin2_v: NF4 KS4 -> 8192 */
#define NF_2S  434176   /* c2_lin1_s: NF4 KS2 -> 4096 */
#define NF_2V  438272   /* c2_lin1_v: NF4 KS2 -> 4096 */
#define NFRAG_TOT 442368

#define NM128 (N_NODES*128)

#define INV_SQRT32   0.17677669529663687f
#define INV_SQRT128  0.08838834764831845f
#define INV_SQRT8    0.3535533905932738f
#define INV_SQRT64   0.125f
#define INV_SQRT2048 0.022097086912079608f
#define INV_SQRT1024 0.03125f
#define INV_SQRT10   0.31622776601683794f
#define INV_SQRT3    0.5773502691896258f
#define SQRT3_C      1.7320508075688772f

__device__ __forceinline__ float siluf(float x){ return x / (1.f + __expf(-x)); }
__device__ __forceinline__ float sigf (float x){ return 1.f / (1.f + __expf(-x)); }
__device__ __forceinline__ u16 f2h(float x){ return __half_as_ushort(__float2half_rn(x)); }
__device__ __forceinline__ float h2f(u16 b){ return __half2float(__ushort_as_half(b)); }
__device__ __forceinline__ f16x8 cvt8(const float* __restrict__ p) {
  f32x4 v0 = *(const f32x4*)p;
  f32x4 v1 = *(const f32x4*)(p + 4);
  f16x8 r;
  r[0]=(_Float16)v0[0]; r[1]=(_Float16)v0[1]; r[2]=(_Float16)v0[2]; r[3]=(_Float16)v0[3];
  r[4]=(_Float16)v1[0]; r[5]=(_Float16)v1[1]; r[6]=(_Float16)v1[2]; r[7]=(_Float16)v1[3];
  return r;
}

__device__ __forceinline__ void geom_core(const float* __restrict__ ev,
                                          float* __restrict__ es, float* __restrict__ sv) {
  float vx = ev[0], vy = ev[1], vz = ev[2];
  float d  = sqrtf(vx*vx + vy*vy + vz*vz);
  float xs = d - 0.25f;
  bool  in = (xs > 0.f) && (xs < 4.0f);
  float safe = xs > 0.f ? xs : 1.f;
  float amp  = in ? 2.0f/safe : 0.f;
  const float PI4 = 0.7853981633974483f;
  #pragma unroll
  for (int k = 0; k < 8; ++k)
    es[k] = amp * sinf((float)(k+1) * PI4 * safe);
  float invd = d > 0.f ? 1.f/d : 1.f;
  sv[0] = SQRT3_C*vx*invd;
  sv[1] = SQRT3_C*vy*invd;
  sv[2] = SQRT3_C*vz*invd;
}

// ---------------- edge geometry, CSR-permuted ----------------
__global__ void k_geom_csr(const float* __restrict__ evec, const int* __restrict__ slot,
                           float* __restrict__ es8, float* __restrict__ shv) {
  int p = blockIdx.x*256 + threadIdx.x;
  if (p >= N_EDGES) return;
  int e = slot[p];
  float es[8], sv[3];
  geom_core(evec + (size_t)e*3, es, sv);
  #pragma unroll
  for (int k = 0; k < 8; ++k) es8[(size_t)p*8+k] = es[k];
  shv[(size_t)p*3+0] = sv[0]; shv[(size_t)p*3+1] = sv[1]; shv[(size_t)p*3+2] = sv[2];
}

// ---------------- edge geometry, identity order (fallback path) ----------------
__global__ void k_geom_id(const float* __restrict__ evec,
                          float* __restrict__ es8, float* __restrict__ shv) {
  int e = blockIdx.x*256 + threadIdx.x;
  if (e >= N_EDGES) return;
  float es[8], sv[3];
  geom_core(evec + (size_t)e*3, es, sv);
  #pragma unroll
  for (int k = 0; k < 8; ++k) es8[(size_t)e*8+k] = es[k];
  shv[(size_t)e*3+0] = sv[0]; shv[(size_t)e*3+1] = sv[1]; shv[(size_t)e*3+2] = sv[2];
}

// ---------------- fallback scalar linear ----------------
__global__ void k_linear128(const float* __restrict__ A, const float* __restrict__ W,
                            float* __restrict__ O, int K, float scale, int total) {
  int t = blockIdx.x*256 + threadIdx.x;
  if (t >= total) return;
  int n = t >> 7, j = t & 127;
  const float* a = A + n*K;
  float a0=0.f,a1=0.f,a2=0.f,a3=0.f;
  for (int k = 0; k < K; k += 4) {
    a0 += a[k+0]*W[(k+0)*128+j];
    a1 += a[k+1]*W[(k+1)*128+j];
    a2 += a[k+2]*W[(k+2)*128+j];
    a3 += a[k+3]*W[(k+3)*128+j];
  }
  O[t] = (a0+a1+a2+a3)*scale;
}

// ---------------- graph node counts + edge histogram (merged) ----------------
__global__ void k_cnthist(const int* __restrict__ batch, const int* __restrict__ edst,
                          float* __restrict__ cnt, int* __restrict__ hist) {
  __shared__ int lc[N_GRAPHS];
  int t = threadIdx.x;
  if (t < N_GRAPHS) lc[t] = 0;
  __syncthreads();
  int i = blockIdx.x*256 + t;
  if (i < N_NODES) atomicAdd(&lc[batch[i]], 1);
  if (i < N_EDGES) atomicAdd(&hist[edst[i]], 1);
  __syncthreads();
  if (t < N_GRAPHS && lc[t] > 0) atomicAdd(&cnt[t], (float)lc[t]);
}

__global__ __launch_bounds__(1024) void k_scanp(const int* __restrict__ hist,
                                                int* __restrict__ offs) {
  __shared__ int wsum[16];
  const int t = threadIdx.x;
  const int lane = t & 63, w = t >> 6;
  const int base = t*10;
  int v[10]; int s = 0;
  #pragma unroll
  for (int i = 0; i < 10; ++i) {
    int idx = base + i;
    int x = (idx < N_NODES) ? hist[idx] : 0;
    s += x; v[i] = s;
  }
  int ws = s;
  #pragma unroll
  for (int d = 1; d < 64; d <<= 1) {
    int u = __shfl_up(ws, d);
    if (lane >= d) ws += u;
  }
  if (lane == 63) wsum[w] = ws;
  __syncthreads();
  if (w == 0) {
    int x = (lane < 16) ? wsum[lane] : 0;
    #pragma unroll
    for (int d = 1; d < 16; d <<= 1) {
      int u = __shfl_up(x, d);
      if (lane >= d) x += u;
    }
    if (lane < 16) wsum[lane] = x;
  }
  __syncthreads();
  int waveoff = (w > 0) ? wsum[w-1] : 0;
  int texcl = waveoff + ws - s;
  if (t == 0) offs[0] = 0;
  #pragma unroll
  for (int i = 0; i < 10; ++i) {
    int idx = base + i;
    if (idx < N_NODES) offs[idx+1] = texcl + v[i];
  }
}

// slot + permuted esrc
__global__ void k_slot(const int* __restrict__ edst, const int* __restrict__ esrc,
                       const int* __restrict__ offs,
                       int* __restrict__ curs, int* __restrict__ slot,
                       int* __restrict__ esrcp) {
  int e = blockIdx.x*256 + threadIdx.x;
  if (e < N_EDGES) {
    int d = edst[e];
    int p = offs[d] + atomicAdd(&curs[d], 1);
    slot[p] = e;
    esrcp[p] = esrc[e];
  }
}

// ---------------- merged weight fragment prep (f16 single-plane, B-frag order) ----------------
struct PD { const float* W; u16* dst; int Keff, N, KS, nElem; float scale; };
struct PD8 { PD d[8]; int nd; int tot; };

__global__ void k_prepmulti(PD8 ds) {
  int stride = gridDim.x*256;
  for (int t = blockIdx.x*256 + threadIdx.x; t < ds.tot; t += stride) {
    int rem = t, i = 0;
    while (i < ds.nd-1 && rem >= ds.d[i].nElem) { rem -= ds.d[i].nElem; ++i; }
    const PD p = ds.d[i];
    int j = rem & 7;
    int l = (rem >> 3) & 63;
    int rest = rem >> 9;
    int ks = rest % p.KS;
    int nf = rest / p.KS;
    int k   = ks*32 + (l >> 4)*8 + j;
    int col = nf*16 + (l & 15);
    float v = (k < p.Keff) ? p.W[(size_t)k*p.N + col]*p.scale : 0.f;
    p.dst[rem] = f2h(v);
  }
}

// ---------------- fused 3-layer edge MLP via f16 MFMA; 32 edges/wave; packed interleaved out ----------------
template<int NF3>
__global__ __launch_bounds__(256) void k_mlp(
    const float* __restrict__ es8,
    const u16* __restrict__ fb1, const u16* __restrict__ fb2,
    const u16* __restrict__ fb3, u16* __restrict__ wbuf) {
  __shared__ __align__(16) _Float16 route[4][2304];
  const int w = threadIdx.x >> 6, l = threadIdx.x & 63;
  const int lrow = l & 15, lhi = l >> 4;
  const int e0 = (blockIdx.x*4 + w)*32;
  _Float16* rt = route[w];
  constexpr int NQ = NF3/4;

  f16x8 a1[2];
  #pragma unroll
  for (int mt = 0; mt < 2; ++mt) {
    f16x8 z = {0,0,0,0,0,0,0,0};
    if (lhi == 0) z = cvt8(es8 + (size_t)(e0 + mt*16 + lrow)*8);
    a1[mt] = z;
  }

  f32x4 acc1[2][4];
  #pragma unroll
  for (int mt = 0; mt < 2; ++mt)
    #pragma unroll
    for (int nf = 0; nf < 4; ++nf) acc1[mt][nf] = (f32x4){0.f,0.f,0.f,0.f};
  #pragma unroll
  for (int nf = 0; nf < 4; ++nf) {
    f16x8 b = *(const f16x8*)(fb1 + nf*512 + l*8);
    #pragma unroll
    for (int mt = 0; mt < 2; ++mt)
      acc1[mt][nf] = __builtin_amdgcn_mfma_f32_16x16x32_f16(a1[mt], b, acc1[mt][nf], 0,0,0);
  }
  #pragma unroll
  for (int mt = 0; mt < 2; ++mt)
    #pragma unroll
    for (int nf = 0; nf < 4; ++nf)
      #pragma unroll
      for (int r = 0; r < 4; ++r) acc1[mt][nf][r] = siluf(acc1[mt][nf][r]);

  f16x8 a2[2][2];
  #pragma unroll
  for (int mt = 0; mt < 2; ++mt)
    #pragma unroll
    for (int nf = 0; nf < 4; ++nf)
      #pragma unroll
      for (int r = 0; r < 4; ++r)
        rt[(mt*16 + lhi*4 + r)*72 + nf*16 + lrow] = (_Float16)acc1[mt][nf][r];
  #pragma unroll
  for (int mt = 0; mt < 2; ++mt)
    #pragma unroll
    for (int ks = 0; ks < 2; ++ks)
      a2[mt][ks] = *(const f16x8*)&rt[(mt*16 + lrow)*72 + ks*32 + lhi*8];

  f32x4 acc2[2][4];
  #pragma unroll
  for (int mt = 0; mt < 2; ++mt)
    #pragma unroll
    for (int nf = 0; nf < 4; ++nf) acc2[mt][nf] = (f32x4){0.f,0.f,0.f,0.f};
  #pragma unroll
  for (int nf = 0; nf < 4; ++nf)
    #pragma unroll
    for (int ks = 0; ks < 2; ++ks) {
      f16x8 b = *(const f16x8*)(fb2 + (nf*2 + ks)*512 + l*8);
      #pragma unroll
      for (int mt = 0; mt < 2; ++mt)
        acc2[mt][nf] = __builtin_amdgcn_mfma_f32_16x16x32_f16(a2[mt][ks], b, acc2[mt][nf], 0,0,0);
    }
  #pragma unroll
  for (int mt = 0; mt < 2; ++mt)
    #pragma unroll
    for (int nf = 0; nf < 4; ++nf)
      #pragma unroll
      for (int r = 0; r < 4; ++r) acc2[mt][nf][r] = siluf(acc2[mt][nf][r]);

  f16x8 a3[2][2];
  #pragma unroll
  for (int mt = 0; mt < 2; ++mt)
    #pragma unroll
    for (int nf = 0; nf < 4; ++nf)
      #pragma unroll
      for (int r = 0; r < 4; ++r)
        rt[(mt*16 + lhi*4 + r)*72 + nf*16 + lrow] = (_Float16)acc2[mt][nf][r];
  #pragma unroll
  for (int mt = 0; mt < 2; ++mt)
    #pragma unroll
    for (int ks = 0; ks < 2; ++ks)
      a3[mt][ks] = *(const f16x8*)&rt[(mt*16 + lrow)*72 + ks*32 + lhi*8];

  #pragma unroll
  for (int cc = 0; cc < 4; ++cc) {
    f32x4 acc3[NQ][2];
    #pragma unroll
    for (int q = 0; q < NQ; ++q)
      #pragma unroll
      for (int mt = 0; mt < 2; ++mt) acc3[q][mt] = (f32x4){0.f,0.f,0.f,0.f};
    #pragma unroll
    for (int q = 0; q < NQ; ++q) {
      const int nf3 = q*4 + cc;
      #pragma unroll
      for (int ks = 0; ks < 2; ++ks) {
        f16x8 b = *(const f16x8*)(fb3 + ((size_t)nf3*2 + ks)*512 + l*8);
        #pragma unroll
        for (int mt = 0; mt < 2; ++mt)
          acc3[q][mt] = __builtin_amdgcn_mfma_f32_16x16x32_f16(a3[mt][ks], b, acc3[q][mt], 0,0,0);
      }
    }
    const int cbase = (cc*16 + lrow)*NQ;
    #pragma unroll
    for (int mt = 0; mt < 2; ++mt)
      #pragma unroll
      for (int r = 0; r < 4; ++r) {
        const size_t rowoff = (size_t)(e0 + mt*16 + lhi*4 + r)*(NF3*16) + cbase;
        if constexpr (NQ == 4) {
          u16x4 pk;
          #pragma unroll
          for (int q = 0; q < 4; ++q) pk[q] = f2h(acc3[q][mt][r]);
          *(u16x4*)(wbuf + rowoff) = pk;
        } else {
          u16x2 pk;
          #pragma unroll
          for (int q = 0; q < 2; ++q) pk[q] = f2h(acc3[q][mt][r]);
          *(u16x2*)(wbuf + rowoff) = pk;
        }
      }
  }
}

// ---------------- generic f16 MFMA GEMM ----------------
template<int KS, int NF>
__global__ __launch_bounds__(512, 4) void k_gemm(
    const float* __restrict__ A, int rstride, int M,
    const u16* __restrict__ fB, float* __restrict__ O) {
  __shared__ __align__(16) _Float16 lB[NF*KS*512];
  const int tid = threadIdx.x;
  const int w = tid >> 6, l = tid & 63;
  const int lrow = l & 15, lhi = l >> 4;
  const int n0 = blockIdx.x*128 + w*16;
  for (int i = tid; i < NF*KS*64; i += 512)
    *(f16x8*)&lB[(size_t)i*8] = *(const f16x8*)&fB[(size_t)i*8];
  f16x8 a[KS];
  {
    int row = n0 + lrow; if (row > M-1) row = M-1;
    #pragma unroll
    for (int ks = 0; ks < KS; ++ks)
      a[ks] = cvt8(A + (size_t)row*rstride + ks*32 + lhi*8);
  }
  __syncthreads();
  f32x4 acc[NF];
  #pragma unroll
  for (int nf = 0; nf < NF; ++nf) acc[nf] = (f32x4){0.f,0.f,0.f,0.f};
  #pragma unroll
  for (int nf = 0; nf < NF; ++nf)
    #pragma unroll
    for (int ks = 0; ks < KS; ++ks) {
      f16x8 b = *(const f16x8*)&lB[((size_t)(nf*KS + ks))*512 + l*8];
      acc[nf] = __builtin_amdgcn_mfma_f32_16x16x32_f16(a[ks], b, acc[nf], 0,0,0);
    }
  #pragma unroll
  for (int nf = 0; nf < NF; ++nf)
    #pragma unroll
    for (int r = 0; r < 4; ++r) {
      int row = n0 + lhi*4 + r;
      if (row < M) O[(size_t)row*(NF*16) + nf*16 + lrow] = acc[nf][r];
    }
}

// ---------------- sc partial (f16) ----------------
template<int KSO>
__global__ __launch_bounds__(512, 4) void k_scp(
    const float* __restrict__ Ao, const float* __restrict__ na,
    const u16* __restrict__ fBc, float* __restrict__ part) {
  __shared__ __align__(16) _Float16 lB[KSO*4096];
  const int tid = threadIdx.x;
  const int w = tid >> 6, l = tid & 63;
  const int lrow = l & 15, lhi = l >> 4;
  const int n0 = blockIdx.x*128 + w*16;
  const int vp = blockIdx.y;

  f16x8 ao[KSO];
  {
    int row = n0 + lrow; if (row > N_NODES-1) row = N_NODES-1;
    #pragma unroll
    for (int ks = 0; ks < KSO; ++ks)
      ao[ks] = cvt8(Ao + (size_t)row*(KSO*32) + ks*32 + lhi*8);
  }

  f32x4 acc[8];
  #pragma unroll
  for (int nf = 0; nf < 8; ++nf) acc[nf] = (f32x4){0.f,0.f,0.f,0.f};

  #pragma unroll
  for (int c = 0; c < 2; ++c) {
    const int v = vp*2 + c;
    __syncthreads();
    for (int i = tid; i < KSO*512; i += 512) {
      int gl = i & 63;
      int rest = i >> 6;
      int ks = rest % KSO;
      int nf = rest / KSO;
      size_t src = (((size_t)(v*8 + nf)*KSO + ks)*64 + gl)*8;
      *(f16x8*)&lB[(size_t)i*8] = *(const f16x8*)&fBc[src];
    }
    __syncthreads();
    f32x4 dacc[8];
    #pragma unroll
    for (int nf = 0; nf < 8; ++nf) dacc[nf] = (f32x4){0.f,0.f,0.f,0.f};
    #pragma unroll
    for (int nf = 0; nf < 8; ++nf)
      #pragma unroll
      for (int ks = 0; ks < KSO; ++ks) {
        f16x8 b = *(const f16x8*)&lB[((size_t)(nf*KSO + ks))*512 + l*8];
        dacc[nf] = __builtin_amdgcn_mfma_f32_16x16x32_f16(ao[ks], b, dacc[nf], 0,0,0);
      }
    #pragma unroll
    for (int r = 0; r < 4; ++r) {
      int row = n0 + lhi*4 + r; if (row > N_NODES-1) row = N_NODES-1;
      float nav = na[(size_t)row*16 + v];
      #pragma unroll
      for (int nf = 0; nf < 8; ++nf) acc[nf][r] += nav * dacc[nf][r];
    }
  }

  float* pp = part + (size_t)vp*NM128;
  #pragma unroll
  for (int nf = 0; nf < 8; ++nf)
    #pragma unroll
    for (int r = 0; r < 4; ++r) {
      int row = n0 + lhi*4 + r;
      if (row < N_NODES) pp[(size_t)row*128 + nf*16 + lrow] = acc[nf][r];
    }
}

// ---------------- fused reduce(9) + gating ----------------
__global__ void k_redgate(const float* __restrict__ part, const float* __restrict__ ov,
                          float* __restrict__ gs_out, float* __restrict__ gv) {
  int t = blockIdx.x*256 + threadIdx.x;
  if (t >= N_NODES*64) return;
  int n = t >> 6, v = t & 63;
  float o1 = 0.f, o2 = 0.f;
  #pragma unroll
  for (int p = 0; p < 9; ++p) {
    const float* pp = part + (size_t)p*NM128 + (size_t)n*128;
    o1 += pp[v]; o2 += pp[64+v];
  }
  float g = siluf(o1), gate = sigf(o2);
  gs_out[(size_t)n*64+v] = g;
  gv[(size_t)n*192 + 0*64 + v] = gate*ov[(size_t)n*192 + 0*64 + v];
  gv[(size_t)n*192 + 1*64 + v] = gate*ov[(size_t)n*192 + 1*64 + v];
  gv[(size_t)n*192 + 2*64 + v] = gate*ov[(size_t)n*192 + 2*64 + v];
}

// ---------------- fused reduce(9) + pooled accumulation (RLE) ----------------
__global__ __launch_bounds__(128) void k_redpool(
    const float* __restrict__ part, const int* __restrict__ batch,
    float* __restrict__ pool) {
  const int j = threadIdx.x;
  const int n0 = blockIdx.x*4;
  float outv[4];
  #pragma unroll
  for (int nn = 0; nn < 4; ++nn) {
    float sv = 0.f;
    #pragma unroll
    for (int p = 0; p < 9; ++p)
      sv += part[(size_t)p*NM128 + (size_t)(n0+nn)*128 + j];
    outv[nn] = sv;
  }
  int b0 = batch[n0], b1 = batch[n0+1], b2 = batch[n0+2], b3 = batch[n0+3];
  float sum = outv[0]; int cur = b0;
  if (b1 == cur) sum += outv[1]; else { atomicAdd(&pool[cur*128+j], sum); cur = b1; sum = outv[1]; }
  if (b2 == cur) sum += outv[2]; else { atomicAdd(&pool[cur*128+j], sum); cur = b2; sum = outv[2]; }
  if (b3 == cur) sum += outv[3]; else { atomicAdd(&pool[cur*128+j], sum); cur = b3; sum = outv[3]; }
  atomicAdd(&pool[cur*128+j], sum);
}

// ---------------- conv1 gather: sequential CSR stream ----------------
__global__ __launch_bounds__(256) void k_gather1(
    const u16* __restrict__ wbuf, const float* __restrict__ shv,
    const int* __restrict__ esrcp, const int* __restrict__ offs,
    const float* __restrict__ h,
    float* __restrict__ n_s, float* __restrict__ n_v) {
  const int wave = threadIdx.x >> 6, lane = threadIdx.x & 63;
  const int n = blockIdx.x*4 + wave;
  if (n >= N_NODES) return;
  const int s0 = offs[n], s1 = offs[n+1];
  float ns0=0.f, ns1=0.f;
  float nv00=0.f,nv01=0.f,nv02=0.f, nv10=0.f,nv11=0.f,nv12=0.f;
  for (int s = s0; s < s1; ++s) {
    int src = esrcp[s];
    u16x4 wv = *(const u16x4*)(wbuf + (size_t)s*256 + lane*4);
    float c0 = h2f(wv[0]), c1 = h2f(wv[1]), c2 = h2f(wv[2]), c3 = h2f(wv[3]);
    float h0 = h[src*128+lane], h1 = h[src*128+64+lane];
    float sv0 = shv[(size_t)s*3+0], sv1 = shv[(size_t)s*3+1], sv2 = shv[(size_t)s*3+2];
    ns0 += c0*h0; ns1 += c1*h1;
    float t0 = c2*h0, t1 = c3*h1;
    nv00 += t0*sv0; nv01 += t0*sv1; nv02 += t0*sv2;
    nv10 += t1*sv0; nv11 += t1*sv1; nv12 += t1*sv2;
  }
  n_s[n*128+lane]    = ns0*INV_SQRT10;
  n_s[n*128+64+lane] = ns1*INV_SQRT10;
  float* nvp = n_v + (size_t)n*384;      // [3][128]
  nvp[0*128+lane]    = nv00*INV_SQRT10;
  nvp[1*128+lane]    = nv01*INV_SQRT10;
  nvp[2*128+lane]    = nv02*INV_SQRT10;
  nvp[0*128+64+lane] = nv10*INV_SQRT10;
  nvp[1*128+64+lane] = nv11*INV_SQRT10;
  nvp[2*128+64+lane] = nv12*INV_SQRT10;
}

// ---------------- conv2 gather: sequential CSR stream; h_v layout [n][3][64] ----------------
__global__ __launch_bounds__(256) void k_gather2(
    const u16* __restrict__ wbuf, const float* __restrict__ shv,
    const int* __restrict__ esrcp, const int* __restrict__ offs,
    const float* __restrict__ h_s, const float* __restrict__ h_v,
    float* __restrict__ n_mid) {
  const int wave = threadIdx.x >> 6, lane = threadIdx.x & 63;
  const int n = blockIdx.x*4 + wave;
  if (n >= N_NODES) return;
  const int s0 = offs[n], s1 = offs[n+1];
  float acc0 = 0.f, acc1 = 0.f;
  for (int s = s0; s < s1; ++s) {
    int src = esrcp[s];
    u16x2 wv = *(const u16x2*)(wbuf + (size_t)s*128 + lane*2);
    float w0 = h2f(wv[0]), w1 = h2f(wv[1]);
    float hs = h_s[src*64+lane];
    const float* hvp = h_v + (size_t)src*192;
    float sv0 = shv[(size_t)s*3+0], sv1 = shv[(size_t)s*3+1], sv2 = shv[(size_t)s*3+2];
    float dot = hvp[lane]*sv0 + hvp[64+lane]*sv1 + hvp[128+lane]*sv2;
    acc0 += w0*hs;
    acc1 += w1*dot;
  }
  n_mid[n*128+lane]    = acc0*INV_SQRT10;
  n_mid[n*128+64+lane] = acc1*INV_SQRT3*INV_SQRT10;
}

// ======== FALLBACK (atomic) kernels — used only if ws too small ========
__global__ __launch_bounds__(512) void k_edge1_at(
    const float* __restrict__ es8, const float* __restrict__ shv,
    const int* __restrict__ esrc, const int* __restrict__ edst,
    const float* __restrict__ h,
    const float* __restrict__ W0, const float* __restrict__ W1, const float* __restrict__ W2,
    float* __restrict__ n_s, float* __restrict__ n_v) {
  __shared__ float lW0[512];
  __shared__ float lW1[4096];
  __shared__ float lW2[16384];
  __shared__ float lA[8][64];
  __shared__ float lB[8][64];
  for (int i = threadIdx.x; i < 512;   i += 512) lW0[i] = W0[i];
  for (int i = threadIdx.x; i < 4096;  i += 512) lW1[i] = W1[i];
  for (int i = threadIdx.x; i < 16384; i += 512) lW2[i] = W2[i];
  __syncthreads();
  const int wave = threadIdx.x >> 6, lane = threadIdx.x & 63;
  const int nw = gridDim.x * 8;
  const int e0 = blockIdx.x*8 + wave;
  const int iters = (N_EDGES + nw - 1) / nw;
  for (int it = 0; it < iters; ++it) {
    int e = e0 + it*nw;
    bool valid = e < N_EDGES;
    float a = 0.f, sv0=0.f, sv1=0.f, sv2=0.f;
    int src = 0, dst = 0;
    if (valid) {
      const float* ep = es8 + e*8;
      sv0 = shv[e*3+0]; sv1 = shv[e*3+1]; sv2 = shv[e*3+2];
      src = esrc[e]; dst = edst[e];
      a = ep[0]*lW0[lane]      + ep[1]*lW0[64+lane]  + ep[2]*lW0[128+lane] + ep[3]*lW0[192+lane]
        + ep[4]*lW0[256+lane]  + ep[5]*lW0[320+lane] + ep[6]*lW0[384+lane] + ep[7]*lW0[448+lane];
      a = siluf(a * INV_SQRT8);
    }
    lA[wave][lane] = a;
    __syncthreads();
    {
      float b0=0.f;
      #pragma unroll
      for (int k = 0; k < 64; ++k) b0 += lA[wave][k]*lW1[k*64+lane];
      lB[wave][lane] = siluf(b0 * INV_SQRT64);
    }
    __syncthreads();
    if (valid) {
      float c0=0.f,c1=0.f,c2=0.f,c3=0.f;
      #pragma unroll
      for (int k = 0; k < 64; ++k) {
        float bk = lB[wave][k];
        const float* r = lW2 + k*256;
        c0 += bk*r[lane]; c1 += bk*r[64+lane]; c2 += bk*r[128+lane]; c3 += bk*r[192+lane];
      }
      float hs0 = h[src*128 + lane];
      float hs1 = h[src*128 + 64 + lane];
      atomicAdd(&n_s[dst*128 + lane],      c0*INV_SQRT64*hs0*INV_SQRT10);
      atomicAdd(&n_s[dst*128 + 64 + lane], c1*INV_SQRT64*hs1*INV_SQRT10);
      float t0 = c2*INV_SQRT64*hs0*INV_SQRT10;
      float t1 = c3*INV_SQRT64*hs1*INV_SQRT10;
      float* nvp = n_v + dst*384;
      atomicAdd(nvp + lane*3+0, t0*sv0);
      atomicAdd(nvp + lane*3+1, t0*sv1);
      atomicAdd(nvp + lane*3+2, t0*sv2);
      atomicAdd(nvp + (64+lane)*3+0, t1*sv0);
      atomicAdd(nvp + (64+lane)*3+1, t1*sv1);
      atomicAdd(nvp + (64+lane)*3+2, t1*sv2);
    }
  }
}

__global__ __launch_bounds__(512) void k_edge2_at(
    const float* __restrict__ es8, const float* __restrict__ shv,
    const int* __restrict__ esrc, const int* __restrict__ edst,
    const float* __restrict__ h_s, const float* __restrict__ h_v,
    const float* __restrict__ W0, const float* __restrict__ W1, const float* __restrict__ W2,
    float* __restrict__ n_mid) {
  __shared__ float lW0[512];
  __shared__ float lW1[4096];
  __shared__ float lW2[8192];
  __shared__ float lA[8][64];
  __shared__ float lB[8][64];
  for (int i = threadIdx.x; i < 512;  i += 512) lW0[i] = W0[i];
  for (int i = threadIdx.x; i < 4096; i += 512) lW1[i] = W1[i];
  for (int i = threadIdx.x; i < 8192; i += 512) lW2[i] = W2[i];
  __syncthreads();
  const int wave = threadIdx.x >> 6, lane = threadIdx.x & 63;
  const int nw = gridDim.x * 8;
  const int e0 = blockIdx.x*8 + wave;
  const int iters = (N_EDGES + nw - 1) / nw;
  for (int it = 0; it < iters; ++it) {
    int e = e0 + it*nw;
    bool valid = e < N_EDGES;
    float a = 0.f, sv0=0.f, sv1=0.f, sv2=0.f;
    int src = 0, dst = 0;
    if (valid) {
      const float* ep = es8 + e*8;
      sv0 = shv[e*3+0]; sv1 = shv[e*3+1]; sv2 = shv[e*3+2];
      src = esrc[e]; dst = edst[e];
      a = ep[0]*lW0[lane]      + ep[1]*lW0[64+lane]  + ep[2]*lW0[128+lane] + ep[3]*lW0[192+lane]
        + ep[4]*lW0[256+lane]  + ep[5]*lW0[320+lane] + ep[6]*lW0[384+lane] + ep[7]*lW0[448+lane];
      a = siluf(a * INV_SQRT8);
    }
    lA[wave][lane] = a;
    __syncthreads();
    {
      float b0=0.f;
      #pragma unroll
      for (int k = 0; k < 64; ++k) b0 += lA[wave][k]*lW1[k*64+lane];
      lB[wave][lane] = siluf(b0 * INV_SQRT64);
    }
    __syncthreads();
    if (valid) {
      float c0=0.f, c1=0.f;
      #pragma unroll
      for (int k = 0; k < 64; ++k) {
        float bk = lB[wave][k];
        const float* r = lW2 + k*128;
        c0 += bk*r[lane]; c1 += bk*r[64+lane];
      }
      float hsv = h_s[src*64 + lane];
      const float* hvp = h_v + src*192 + lane*3;
      float dotv = hvp[0]*sv0 + hvp[1]*sv1 + hvp[2]*sv2;
      atomicAdd(&n_mid[dst*128 + lane],      c0*INV_SQRT64*hsv*INV_SQRT10);
      atomicAdd(&n_mid[dst*128 + 64 + lane], c1*INV_SQRT64*dotv*INV_SQRT3*INV_SQRT10);
    }
  }
}

// ---------------- FALLBACK conv1 node pass (full, old n_v layout) ----------------
__global__ __launch_bounds__(128) void k_node1(
    const float* __restrict__ n_s, const float* __restrict__ n_v,
    const float* __restrict__ s,   const float* __restrict__ na,
    const float* __restrict__ Wls, const float* __restrict__ Wlv,
    const float* __restrict__ Csc, const float* __restrict__ W2s, const float* __restrict__ W2v,
    float* __restrict__ gs_out, float* __restrict__ hs_out, float* __restrict__ hv_out) {
  __shared__ float l_ns[512], l_s[512], l_na[64], l_nv[1536];
  __shared__ float l_outs[512], l_ov[768], l_gs[256], l_gv[768];
  const int j = threadIdx.x;
  const int n0 = blockIdx.x*4;
  for (int i = j; i < 512;  i += 128) { l_ns[i] = n_s[n0*128+i]; l_s[i] = s[n0*128+i]; }
  for (int i = j; i < 1536; i += 128) l_nv[i] = n_v[n0*384+i];
  if (j < 64) l_na[j] = na[n0*16+j];
  __syncthreads();

  float accs[4] = {0.f,0.f,0.f,0.f};
  for (int k = 0; k < 128; ++k) {
    float w = Wls[k*128+j];
    accs[0] += l_ns[k]*w; accs[1] += l_ns[128+k]*w;
    accs[2] += l_ns[256+k]*w; accs[3] += l_ns[384+k]*w;
  }
  float accc[4] = {0.f,0.f,0.f,0.f};
  for (int vt = 0; vt < 16; vt += 4) {
    float a0[4],a1[4],a2[4],a3[4];
    #pragma unroll
    for (int n = 0; n < 4; ++n) {
      a0[n]=l_na[n*16+vt]; a1[n]=l_na[n*16+vt+1];
      a2[n]=l_na[n*16+vt+2]; a3[n]=l_na[n*16+vt+3];
    }
    for (int u = 0; u < 128; ++u) {
      const float* cp = Csc + (u*16+vt)*128 + j;
      float c0=cp[0], c1=cp[128], c2=cp[256], c3=cp[384];
      float s0=l_s[u], s1=l_s[128+u], s2=l_s[256+u], s3=l_s[384+u];
      accc[0] += s0*(a0[0]*c0 + a1[0]*c1 + a2[0]*c2 + a3[0]*c3);
      accc[1] += s1*(a0[1]*c0 + a1[1]*c1 + a2[1]*c2 + a3[1]*c3);
      accc[2] += s2*(a0[2]*c0 + a1[2]*c1 + a2[2]*c2 + a3[2]*c3);
      accc[3] += s3*(a0[3]*c0 + a1[3]*c1 + a2[3]*c2 + a3[3]*c3);
    }
  }
  #pragma unroll
  for (int n = 0; n < 4; ++n)
    l_outs[n*128+j] = accs[n]*INV_SQRT128 + accc[n]*INV_SQRT2048;

  const int jj = j & 63, hh = j >> 6;
  float ov[2][3] = {{0.f,0.f,0.f},{0.f,0.f,0.f}};
  for (int u = 0; u < 128; ++u) {
    float w = Wlv[u*64+jj];
    #pragma unroll
    for (int t = 0; t < 2; ++t) {
      int n = 2*hh+t;
      ov[t][0] += l_nv[n*384+u*3+0]*w;
      ov[t][1] += l_nv[n*384+u*3+1]*w;
      ov[t][2] += l_nv[n*384+u*3+2]*w;
    }
  }
  #pragma unroll
  for (int t = 0; t < 2; ++t) {
    int n = 2*hh+t;
    l_ov[n*192+jj*3+0] = ov[t][0]*INV_SQRT128;
    l_ov[n*192+jj*3+1] = ov[t][1]*INV_SQRT128;
    l_ov[n*192+jj*3+2] = ov[t][2]*INV_SQRT128;
  }
  __syncthreads();

  #pragma unroll
  for (int t = 0; t < 2; ++t) {
    int n = 2*hh+t;
    float gv_s = siluf(l_outs[n*128+jj]);
    float gate = sigf (l_outs[n*128+64+jj]);
    l_gs[n*64+jj] = gv_s;
    gs_out[(n0+n)*64+jj] = gv_s;
    l_gv[n*192+jj*3+0] = gate*l_ov[n*192+jj*3+0];
    l_gv[n*192+jj*3+1] = gate*l_ov[n*192+jj*3+1];
    l_gv[n*192+jj*3+2] = gate*l_ov[n*192+jj*3+2];
  }
  __syncthreads();

  float ha[2] = {0.f,0.f};
  for (int k = 0; k < 64; ++k) {
    float w = W2s[k*64+jj];
    ha[0] += l_gs[(2*hh+0)*64+k]*w;
    ha[1] += l_gs[(2*hh+1)*64+k]*w;
  }
  hs_out[(n0+2*hh+0)*64+jj] = ha[0]*INV_SQRT64;
  hs_out[(n0+2*hh+1)*64+jj] = ha[1]*INV_SQRT64;

  float hv[2][3] = {{0.f,0.f,0.f},{0.f,0.f,0.f}};
  for (int u = 0; u < 64; ++u) {
    float w = W2v[u*64+jj];
    #pragma unroll
    for (int t = 0; t < 2; ++t) {
      int n = 2*hh+t;
      hv[t][0] += l_gv[n*192+u*3+0]*w;
      hv[t][1] += l_gv[n*192+u*3+1]*w;
      hv[t][2] += l_gv[n*192+u*3+2]*w;
    }
  }
  #pragma unroll
  for (int t = 0; t < 2; ++t) {
    int n = 2*hh+t;
    hv_out[(n0+n)*192+jj*3+0] = hv[t][0]*INV_SQRT64;
    hv_out[(n0+n)*192+jj*3+1] = hv[t][1]*INV_SQRT64;
    hv_out[(n0+n)*192+jj*3+2] = hv[t][2]*INV_SQRT64;
  }
}

// ---------------- FALLBACK conv2 node pass + pooling ----------------
__global__ __launch_bounds__(128) void k_node2(
    const float* __restrict__ n_mid, const float* __restrict__ gs,
    const float* __restrict__ na, const int* __restrict__ batch,
    const float* __restrict__ W, const float* __restrict__ Csc,
    float* __restrict__ pool) {
  __shared__ float l_nm[512], l_gs[256], l_na[64];
  const int j = threadIdx.x;
  const int n0 = blockIdx.x*4;
  for (int i = j; i < 512; i += 128) l_nm[i] = n_mid[n0*128+i];
  for (int i = j; i < 256; i += 128) l_gs[i] = gs[n0*64+i];
  if (j < 64) l_na[j] = na[n0*16+j];
  __syncthreads();
  float acc[4] = {0.f,0.f,0.f,0.f};
  for (int k = 0; k < 128; ++k) {
    float w = W[k*128+j];
    acc[0] += l_nm[k]*w; acc[1] += l_nm[128+k]*w;
    acc[2] += l_nm[256+k]*w; acc[3] += l_nm[384+k]*w;
  }
  float acc2[4] = {0.f,0.f,0.f,0.f};
  for (int vt = 0; vt < 16; vt += 4) {
    float a0[4],a1[4],a2[4],a3[4];
    #pragma unroll
    for (int n = 0; n < 4; ++n) {
      a0[n]=l_na[n*16+vt]; a1[n]=l_na[n*16+vt+1];
      a2[n]=l_na[n*16+vt+2]; a3[n]=l_na[n*16+vt+3];
    }
    for (int u = 0; u < 64; ++u) {
      const float* cp = Csc + (u*16+vt)*128 + j;
      float c0=cp[0], c1=cp[128], c2=cp[256], c3=cp[384];
      float s0=l_gs[u], s1=l_gs[64+u], s2=l_gs[128+u], s3=l_gs[192+u];
      acc2[0] += s0*(a0[0]*c0 + a1[0]*c1 + a2[0]*c2 + a3[0]*c3);
      acc2[1] += s1*(a0[1]*c0 + a1[1]*c1 + a2[1]*c2 + a3[1]*c3);
      acc2[2] += s2*(a0[2]*c0 + a1[2]*c1 + a2[2]*c2 + a3[2]*c3);
      acc2[3] += s3*(a0[3]*c0 + a1[3]*c1 + a2[3]*c2 + a3[3]*c3);
    }
  }
  float outv[4];
  #pragma unroll
  for (int n = 0; n < 4; ++n)
    outv[n] = acc[n]*INV_SQRT128 + acc2[n]*INV_SQRT1024;
  int b0 = batch[n0], b1 = batch[n0+1], b2 = batch[n0+2], b3 = batch[n0+3];
  float sum = outv[0]; int cur = b0;
  if (b1 == cur) sum += outv[1]; else { atomicAdd(&pool[cur*128+j], sum); cur = b1; sum = outv[1]; }
  if (b2 == cur) sum += outv[2]; else { atomicAdd(&pool[cur*128+j], sum); cur = b2; sum = outv[2]; }
  if (b3 == cur) sum += outv[3]; else { atomicAdd(&pool[cur*128+j], sum); cur = b3; sum = outv[3]; }
  atomicAdd(&pool[cur*128+j], sum);
}

// ---------------- readout head: one block per graph, wave-parallel reduce ----------------
__global__ __launch_bounds__(128) void k_head(
    const float* __restrict__ pool, const float* __restrict__ cnt,
    const float* __restrict__ Wr1, const float* __restrict__ Wr2,
    float* __restrict__ out) {
  __shared__ float lp[128];
  __shared__ float wsum[2];
  const int j = threadIdx.x;
  const int g = blockIdx.x;
  float inv = 1.f / fmaxf(cnt[g], 1.f);
  lp[j] = pool[(size_t)g*128 + j]*inv;
  __syncthreads();
  float acc = 0.f;
  for (int k = 0; k < 128; ++k) acc += lp[k]*Wr1[k*128+j];
  float val = siluf(acc*INV_SQRT128) * Wr2[j];
  #pragma unroll
  for (int d = 32; d > 0; d >>= 1) val += __shfl_down(val, d);
  if ((j & 63) == 0) wsum[j >> 6] = val;
  __syncthreads();
  if (j == 0) out[g] = (wsum[0] + wsum[1]) * INV_SQRT128;
}

extern "C" void kernel_launch(void* const* d_in, const int* in_sizes, int n_in,
                              void* d_out, int out_size, void* d_ws, size_t ws_size,
                              hipStream_t stream) {
  const float* x         = (const float*)d_in[0];
  const float* node_attr = (const float*)d_in[1];
  const int*   esrc      = (const int*)d_in[2];
  const int*   edst      = (const int*)d_in[3];
  const float* evec      = (const float*)d_in[4];
  const int*   batch     = (const int*)d_in[5];
  const float* W_embed   = (const float*)d_in[6];
  const float* c1_lin1   = (const float*)d_in[7];
  const float* c1_fc_w0  = (const float*)d_in[8];
  const float* c1_fc_w1  = (const float*)d_in[9];
  const float* c1_fc_w2  = (const float*)d_in[10];
  const float* c1_lin2_s = (const float*)d_in[11];
  const float* c1_lin2_v = (const float*)d_in[12];
  const float* c1_sc     = (const float*)d_in[13];
  const float* c2_lin1_s = (const float*)d_in[14];
  const float* c2_lin1_v = (const float*)d_in[15];
  const float* c2_fc_w0  = (const float*)d_in[16];
  const float* c2_fc_w1  = (const float*)d_in[17];
  const float* c2_fc_w2  = (const float*)d_in[18];
  const float* c2_lin2   = (const float*)d_in[19];
  const float* c2_sc     = (const float*)d_in[20];
  const float* Wr1       = (const float*)d_in[21];
  const float* Wr2       = (const float*)d_in[22];

  float* ws    = (float*)d_ws;
  float* es8   = ws + OFF_ES8;
  float* shv   = ws + OFF_SHV;
  float* s_    = ws + OFF_S;
  float* h_    = ws + OFF_H;
  float* gs_   = ws + OFF_GS;
  float* hs_   = ws + OFF_HS;
  float* hv_   = ws + OFF_HV;
  float* ns_   = ws + OFF_NS;
  float* nv_   = ws + OFF_NV;
  float* nmid_ = ws + OFF_NMID;
  float* pool_ = ws + OFF_POOL;
  float* cnt_  = ws + OFF_CNT;
  int*   hist_ = (int*)(ws + OFF_HIST);
  int*   curs_ = (int*)(ws + OFF_CURS);
  int*   offs_ = (int*)(ws + OFF_OFFS);
  u16*   frag_ = (u16*)(ws + OFF_FRAG);
  int*   slot_ = (int*)(ws + OFF_SLOT);
  float* wbuf_ = ws + OFF_WBUF;
  u16*   wb16_ = (u16*)wbuf_;

  // upper-wbuf carve-outs
  float* out1_  = wbuf_ + (size_t)N_EDGES*128;                 // reserved (layout stability)
  u16*   nfrag_ = (u16*)(out1_ + (size_t)NM128);               // 442368 u16
  float* part_  = out1_ + (size_t)NM128 + NFRAG_TOT/2;         // 9 x 1.28M floats
  float* ov_    = part_ + (size_t)9*NM128;                     // 1.92M floats
  int*   esrcp_ = (int*)(ov_ + (size_t)N_NODES*192);           // N_EDGES ints
  float* gv_    = nv_;                                         // aliases nv (dead after ov GEMM)

  const bool big = ws_size >= WS_NEED_BYTES;

  if (big) {
    hipMemsetAsync(pool_, 0, (size_t)(OFF_OFFS - OFF_POOL)*sizeof(float), stream);
    k_cnthist<<<(N_EDGES+255)/256, 256, 0, stream>>>(batch, edst, cnt_, hist_);
    k_scanp<<<1, 1024, 0, stream>>>(hist_, offs_);
    k_slot<<<(N_EDGES+255)/256, 256, 0, stream>>>(edst, esrc, offs_, curs_, slot_, esrcp_);
    k_geom_csr<<<(N_EDGES+255)/256, 256, 0, stream>>>(evec, slot_, es8, shv);

    {
      PD8 m{};
      m.d[0] = {c1_fc_w0, frag_ + F_B1,  8,  64,  1, 2048,  INV_SQRT8};
      m.d[1] = {c1_fc_w1, frag_ + F_B2,  64, 64,  2, 4096,  INV_SQRT64};
      m.d[2] = {c1_fc_w2, frag_ + F_B3,  64, 256, 2, 16384, INV_SQRT64};
      m.d[3] = {c2_fc_w0, frag_ + F_B1b, 8,  64,  1, 2048,  INV_SQRT8};
      m.d[4] = {c2_fc_w1, frag_ + F_B2b, 64, 64,  2, 4096,  INV_SQRT64};
      m.d[5] = {c2_fc_w2, frag_ + F_B3b, 64, 128, 2, 8192,  INV_SQRT64};
      m.d[6] = {W_embed,  frag_ + F_WE,  32, 128, 1, 4096,  INV_SQRT32};
      m.d[7] = {c1_lin1,  frag_ + F_L1,  128,128, 4, 16384, INV_SQRT128};
      m.nd = 8; m.tot = FRAG_TOT;
      k_prepmulti<<<224, 256, 0, stream>>>(m);
    }

    k_gemm<1,8><<<79, 512, 0, stream>>>(x,  32,  N_NODES, frag_ + F_WE, s_);
    k_gemm<4,8><<<79, 512, 0, stream>>>(s_, 128, N_NODES, frag_ + F_L1, h_);

    k_mlp<16><<<1250, 256, 0, stream>>>(es8, frag_ + F_B1, frag_ + F_B2, frag_ + F_B3, wb16_);
    k_gather1<<<(N_NODES+3)/4, 256, 0, stream>>>(wb16_, shv, esrcp_, offs_, h_, ns_, nv_);

    {
      PD8 m{};
      m.d[0] = {c1_lin2_s, nfrag_ + NF_WLS, 128, 128,  4, 16384,  INV_SQRT128};
      m.d[1] = {c1_sc,     nfrag_ + NF_C1,  128, 2048, 4, 262144, INV_SQRT2048};
      m.d[2] = {c2_lin2,   nfrag_ + NF_W2,  128, 128,  4, 16384,  INV_SQRT128};
      m.d[3] = {c2_sc,     nfrag_ + NF_C2,  64,  2048, 2, 131072, INV_SQRT1024};
      m.d[4] = {c1_lin2_v, nfrag_ + NF_LV,  128, 64,   4, 8192,   INV_SQRT128};
      m.d[5] = {c2_lin1_s, nfrag_ + NF_2S,  64,  64,   2, 4096,   INV_SQRT64};
      m.d[6] = {c2_lin1_v, nfrag_ + NF_2V,  64,  64,   2, 4096,   INV_SQRT64};
      m.nd = 7; m.tot = NFRAG_TOT;
      k_prepmulti<<<864, 256, 0, stream>>>(m);
    }

    k_gemm<4,8><<<79, 512, 0, stream>>>(ns_, 128, N_NODES, nfrag_ + NF_WLS, part_ + (size_t)8*NM128);
    k_scp<4><<<dim3(79,8), 512, 0, stream>>>(s_, node_attr, nfrag_ + NF_C1, part_);
    k_gemm<4,4><<<235, 512, 0, stream>>>(nv_, 128, N_NODES*3, nfrag_ + NF_LV, ov_);
    k_redgate<<<(N_NODES*64+255)/256, 256, 0, stream>>>(part_, ov_, gs_, gv_);
    k_gemm<2,4><<<79, 512, 0, stream>>>(gs_, 64, N_NODES, nfrag_ + NF_2S, hs_);
    k_gemm<2,4><<<235, 512, 0, stream>>>(gv_, 64, N_NODES*3, nfrag_ + NF_2V, hv_);

    k_mlp<8><<<1250, 256, 0, stream>>>(es8, frag_ + F_B1b, frag_ + F_B2b, frag_ + F_B3b, wb16_);
    k_gather2<<<(N_NODES+3)/4, 256, 0, stream>>>(wb16_, shv, esrcp_, offs_, hs_, hv_, nmid_);

    k_gemm<4,8><<<79, 512, 0, stream>>>(nmid_, 128, N_NODES, nfrag_ + NF_W2, part_ + (size_t)8*NM128);
    k_scp<2><<<dim3(79,8), 512, 0, stream>>>(gs_, node_attr, nfrag_ + NF_C2, part_);
    k_redpool<<<N_NODES/4, 128, 0, stream>>>(part_, batch, pool_);
  } else {
    hipMemsetAsync(ns_, 0, (size_t)(OFF_HIST - OFF_NS)*sizeof(float), stream);
    k_geom_id<<<N_EDGES/256, 256, 0, stream>>>(evec, es8, shv);
    k_linear128<<<(N_NODES*128)/256, 256, 0, stream>>>(x,  W_embed, s_, 32,  INV_SQRT32,  N_NODES*128);
    k_linear128<<<(N_NODES*128)/256, 256, 0, stream>>>(s_, c1_lin1, h_, 128, INV_SQRT128, N_NODES*128);
    k_cnthist<<<(N_EDGES+255)/256, 256, 0, stream>>>(batch, edst, cnt_, hist_);
    k_edge1_at<<<256, 512, 0, stream>>>(es8, shv, esrc, edst, h_,
                                        c1_fc_w0, c1_fc_w1, c1_fc_w2, ns_, nv_);
    k_node1<<<N_NODES/4, 128, 0, stream>>>(ns_, nv_, s_, node_attr,
                                           c1_lin2_s, c1_lin2_v, c1_sc,
                                           c2_lin1_s, c2_lin1_v, gs_, hs_, hv_);
    k_edge2_at<<<512, 512, 0, stream>>>(es8, shv, esrc, edst, hs_, hv_,
                                        c2_fc_w0, c2_fc_w1, c2_fc_w2, nmid_);
    k_node2<<<N_NODES/4, 128, 0, stream>>>(nmid_, gs_, node_attr, batch,
                                           c2_lin2, c2_sc, pool_);
  }

  k_head<<<N_GRAPHS, 128, 0, stream>>>(pool_, cnt_, Wr1, Wr2, (float*)d_out);
}

// Round 13
// 261.165 us; speedup vs baseline: 4.8058x; 1.0547x over previous
//
#include <hip/hip_runtime.h>
#include <hip/hip_fp16.h>

#define N_NODES 10000
#define N_EDGES 160000
#define N_GRAPHS 16

typedef __attribute__((ext_vector_type(8))) _Float16 f16x8;
typedef __attribute__((ext_vector_type(4))) float f32x4;
typedef __attribute__((ext_vector_type(4))) unsigned short u16x4;
typedef __attribute__((ext_vector_type(2))) unsigned short u16x2;
typedef unsigned int uint32;
typedef unsigned short u16;

// ---- workspace layout (float offsets) ----
#define OFF_ES8  0
#define OFF_SHV  (OFF_ES8 + N_EDGES*8)
#define OFF_S    (OFF_SHV + N_EDGES*3)
#define OFF_H    (OFF_S   + N_NODES*128)
#define OFF_GS   (OFF_H   + N_NODES*128)
#define OFF_HS   (OFF_GS  + N_NODES*64)
#define OFF_HV   (OFF_HS  + N_NODES*64)
#define OFF_NS   (OFF_HV  + N_NODES*192)   /* fallback zero-region start */
#define OFF_NV   (OFF_NS  + N_NODES*128)
#define OFF_NMID (OFF_NV  + N_NODES*384)
#define OFF_POOL (OFF_NMID+ N_NODES*128)   /* new-path zero-region start */
#define OFF_CNT  (OFF_POOL+ N_GRAPHS*128)
#define OFF_HIST (OFF_CNT + N_GRAPHS)
#define OFF_CURS (OFF_HIST+ N_NODES)
#define OFF_OFFS (OFF_CURS+ N_NODES)       /* new-path zero-region end (excl) */
#define OFF_FRAG (OFF_OFFS+ N_NODES + 16)  /* persistent frags: 57344 u16 (f16 single-plane) */
#define OFF_SLOT (OFF_FRAG+ 57344)         /* esrcp: N_EDGES ints */
#define OFF_WBUF (OFF_SLOT+ N_EDGES)
#define WBUF_FLOATS ((size_t)N_EDGES*256)
#define WS_NEED_BYTES ((size_t)(OFF_WBUF + WBUF_FLOATS) * 4)

// persistent frag sub-offsets in u16 (single-plane f16: NF*KS*512 each)
#define F_B1   0        /* conv1 L1: NF4 KS1 -> 2048  */
#define F_B2   2048     /* conv1 L2: NF4 KS2 -> 4096  */
#define F_B3   6144     /* conv1 L3: NF16 KS2 -> 16384 */
#define F_B1b  22528
#define F_B2b  24576
#define F_B3b  28672    /* conv2 L3: NF8 KS2 -> 8192 */
#define F_WE   36864    /* W_embed: NF8 KS1 -> 4096 */
#define F_L1   40960    /* c1_lin1: NF8 KS4 -> 16384 */
#define FRAG_TOT 57344

// node-frag sub-offsets in u16
#define NF_WLS 0        /* c1_lin2_s: NF8 KS4 -> 16384 */
#define NF_C1  16384    /* c1_sc:   NF128 KS4 -> 262144 */
#define NF_W2  278528   /* c2_lin2:  NF8 KS4 -> 16384 */
#define NF_C2  294912   /* c2_sc:   NF128 KS2 -> 131072 */
#define NF_LV  425984   /* c1_lin2_v: NF4 KS4 -> 8192 */
#define NF_2S  434176   /* c2_lin1_s: NF4 KS2 -> 4096 */
#define NF_2V  438272   /* c2_lin1_v: NF4 KS2 -> 4096 */
#define NFRAG_TOT 442368

#define NM128 (N_NODES*128)

#define INV_SQRT32   0.17677669529663687f
#define INV_SQRT128  0.08838834764831845f
#define INV_SQRT8    0.3535533905932738f
#define INV_SQRT64   0.125f
#define INV_SQRT2048 0.022097086912079608f
#define INV_SQRT1024 0.03125f
#define INV_SQRT10   0.31622776601683794f
#define INV_SQRT3    0.5773502691896258f
#define SQRT3_C      1.7320508075688772f

__device__ __forceinline__ float siluf(float x){ return x / (1.f + __expf(-x)); }
__device__ __forceinline__ float sigf (float x){ return 1.f / (1.f + __expf(-x)); }
__device__ __forceinline__ u16 f2h(float x){ return __half_as_ushort(__float2half_rn(x)); }
__device__ __forceinline__ float h2f(u16 b){ return __half2float(__ushort_as_half(b)); }
__device__ __forceinline__ f16x8 cvt8(const float* __restrict__ p) {
  f32x4 v0 = *(const f32x4*)p;
  f32x4 v1 = *(const f32x4*)(p + 4);
  f16x8 r;
  r[0]=(_Float16)v0[0]; r[1]=(_Float16)v0[1]; r[2]=(_Float16)v0[2]; r[3]=(_Float16)v0[3];
  r[4]=(_Float16)v1[0]; r[5]=(_Float16)v1[1]; r[6]=(_Float16)v1[2]; r[7]=(_Float16)v1[3];
  return r;
}

__device__ __forceinline__ void geom_core(const float* __restrict__ ev,
                                          float* __restrict__ es, float* __restrict__ sv) {
  float vx = ev[0], vy = ev[1], vz = ev[2];
  float d  = sqrtf(vx*vx + vy*vy + vz*vz);
  float xs = d - 0.25f;
  bool  in = (xs > 0.f) && (xs < 4.0f);
  float safe = xs > 0.f ? xs : 1.f;
  float amp  = in ? 2.0f/safe : 0.f;
  const float PI4 = 0.7853981633974483f;
  #pragma unroll
  for (int k = 0; k < 8; ++k)
    es[k] = amp * sinf((float)(k+1) * PI4 * safe);
  float invd = d > 0.f ? 1.f/d : 1.f;
  sv[0] = SQRT3_C*vx*invd;
  sv[1] = SQRT3_C*vy*invd;
  sv[2] = SQRT3_C*vz*invd;
}

// ---------------- fused CSR slot assignment + edge geometry (f16 es8) ----------------
__global__ void k_slotgeom(const int* __restrict__ edst, const int* __restrict__ esrc,
                           const float* __restrict__ evec, const int* __restrict__ offs,
                           int* __restrict__ curs, int* __restrict__ esrcp,
                           u16* __restrict__ es8h, float* __restrict__ shv) {
  int e = blockIdx.x*256 + threadIdx.x;
  if (e >= N_EDGES) return;
  int d = edst[e];
  int p = offs[d] + atomicAdd(&curs[d], 1);
  esrcp[p] = esrc[e];
  float es[8], sv[3];
  geom_core(evec + (size_t)e*3, es, sv);
  u16x4 a, b;
  #pragma unroll
  for (int k = 0; k < 4; ++k) { a[k] = f2h(es[k]); b[k] = f2h(es[k+4]); }
  *(u16x4*)(es8h + (size_t)p*8)     = a;
  *(u16x4*)(es8h + (size_t)p*8 + 4) = b;
  shv[(size_t)p*3+0] = sv[0]; shv[(size_t)p*3+1] = sv[1]; shv[(size_t)p*3+2] = sv[2];
}

// ---------------- edge geometry, identity order (fallback path, f32) ----------------
__global__ void k_geom_id(const float* __restrict__ evec,
                          float* __restrict__ es8, float* __restrict__ shv) {
  int e = blockIdx.x*256 + threadIdx.x;
  if (e >= N_EDGES) return;
  float es[8], sv[3];
  geom_core(evec + (size_t)e*3, es, sv);
  #pragma unroll
  for (int k = 0; k < 8; ++k) es8[(size_t)e*8+k] = es[k];
  shv[(size_t)e*3+0] = sv[0]; shv[(size_t)e*3+1] = sv[1]; shv[(size_t)e*3+2] = sv[2];
}

// ---------------- fallback scalar linear ----------------
__global__ void k_linear128(const float* __restrict__ A, const float* __restrict__ W,
                            float* __restrict__ O, int K, float scale, int total) {
  int t = blockIdx.x*256 + threadIdx.x;
  if (t >= total) return;
  int n = t >> 7, j = t & 127;
  const float* a = A + n*K;
  float a0=0.f,a1=0.f,a2=0.f,a3=0.f;
  for (int k = 0; k < K; k += 4) {
    a0 += a[k+0]*W[(k+0)*128+j];
    a1 += a[k+1]*W[(k+1)*128+j];
    a2 += a[k+2]*W[(k+2)*128+j];
    a3 += a[k+3]*W[(k+3)*128+j];
  }
  O[t] = (a0+a1+a2+a3)*scale;
}

// ---------------- graph node counts + edge histogram (merged) ----------------
__global__ void k_cnthist(const int* __restrict__ batch, const int* __restrict__ edst,
                          float* __restrict__ cnt, int* __restrict__ hist) {
  __shared__ int lc[N_GRAPHS];
  int t = threadIdx.x;
  if (t < N_GRAPHS) lc[t] = 0;
  __syncthreads();
  int i = blockIdx.x*256 + t;
  if (i < N_NODES) atomicAdd(&lc[batch[i]], 1);
  if (i < N_EDGES) atomicAdd(&hist[edst[i]], 1);
  __syncthreads();
  if (t < N_GRAPHS && lc[t] > 0) atomicAdd(&cnt[t], (float)lc[t]);
}

__global__ __launch_bounds__(1024) void k_scanp(const int* __restrict__ hist,
                                                int* __restrict__ offs) {
  __shared__ int wsum[16];
  const int t = threadIdx.x;
  const int lane = t & 63, w = t >> 6;
  const int base = t*10;
  int v[10]; int s = 0;
  #pragma unroll
  for (int i = 0; i < 10; ++i) {
    int idx = base + i;
    int x = (idx < N_NODES) ? hist[idx] : 0;
    s += x; v[i] = s;
  }
  int ws = s;
  #pragma unroll
  for (int d = 1; d < 64; d <<= 1) {
    int u = __shfl_up(ws, d);
    if (lane >= d) ws += u;
  }
  if (lane == 63) wsum[w] = ws;
  __syncthreads();
  if (w == 0) {
    int x = (lane < 16) ? wsum[lane] : 0;
    #pragma unroll
    for (int d = 1; d < 16; d <<= 1) {
      int u = __shfl_up(x, d);
      if (lane >= d) x += u;
    }
    if (lane < 16) wsum[lane] = x;
  }
  __syncthreads();
  int waveoff = (w > 0) ? wsum[w-1] : 0;
  int texcl = waveoff + ws - s;
  if (t == 0) offs[0] = 0;
  #pragma unroll
  for (int i = 0; i < 10; ++i) {
    int idx = base + i;
    if (idx < N_NODES) offs[idx+1] = texcl + v[i];
  }
}

// ---------------- merged weight fragment prep (f16 single-plane, B-frag order) ----------------
struct PD { const float* W; u16* dst; int Keff, N, KS, nElem; float scale; };
struct PDS { PD d[15]; int nd; int tot; };

__global__ void k_prepmulti(PDS ds) {
  int stride = gridDim.x*256;
  for (int t = blockIdx.x*256 + threadIdx.x; t < ds.tot; t += stride) {
    int rem = t, i = 0;
    while (i < ds.nd-1 && rem >= ds.d[i].nElem) { rem -= ds.d[i].nElem; ++i; }
    const PD p = ds.d[i];
    int j = rem & 7;
    int l = (rem >> 3) & 63;
    int rest = rem >> 9;
    int ks = rest % p.KS;
    int nf = rest / p.KS;
    int k   = ks*32 + (l >> 4)*8 + j;
    int col = nf*16 + (l & 15);
    float v = (k < p.Keff) ? p.W[(size_t)k*p.N + col]*p.scale : 0.f;
    p.dst[rem] = f2h(v);
  }
}

// ---------------- fused 3-layer edge MLP via f16 MFMA; 32 edges/wave; packed interleaved out ----------------
template<int NF3>
__global__ __launch_bounds__(256) void k_mlp(
    const u16* __restrict__ es8h,
    const u16* __restrict__ fb1, const u16* __restrict__ fb2,
    const u16* __restrict__ fb3, u16* __restrict__ wbuf) {
  __shared__ __align__(16) _Float16 route[4][2304];
  const int w = threadIdx.x >> 6, l = threadIdx.x & 63;
  const int lrow = l & 15, lhi = l >> 4;
  const int e0 = (blockIdx.x*4 + w)*32;
  _Float16* rt = route[w];
  constexpr int NQ = NF3/4;

  f16x8 a1[2];
  #pragma unroll
  for (int mt = 0; mt < 2; ++mt) {
    f16x8 z = {0,0,0,0,0,0,0,0};
    if (lhi == 0) z = *(const f16x8*)(es8h + (size_t)(e0 + mt*16 + lrow)*8);
    a1[mt] = z;
  }

  f32x4 acc1[2][4];
  #pragma unroll
  for (int mt = 0; mt < 2; ++mt)
    #pragma unroll
    for (int nf = 0; nf < 4; ++nf) acc1[mt][nf] = (f32x4){0.f,0.f,0.f,0.f};
  #pragma unroll
  for (int nf = 0; nf < 4; ++nf) {
    f16x8 b = *(const f16x8*)(fb1 + nf*512 + l*8);
    #pragma unroll
    for (int mt = 0; mt < 2; ++mt)
      acc1[mt][nf] = __builtin_amdgcn_mfma_f32_16x16x32_f16(a1[mt], b, acc1[mt][nf], 0,0,0);
  }
  #pragma unroll
  for (int mt = 0; mt < 2; ++mt)
    #pragma unroll
    for (int nf = 0; nf < 4; ++nf)
      #pragma unroll
      for (int r = 0; r < 4; ++r) acc1[mt][nf][r] = siluf(acc1[mt][nf][r]);

  f16x8 a2[2][2];
  #pragma unroll
  for (int mt = 0; mt < 2; ++mt)
    #pragma unroll
    for (int nf = 0; nf < 4; ++nf)
      #pragma unroll
      for (int r = 0; r < 4; ++r)
        rt[(mt*16 + lhi*4 + r)*72 + nf*16 + lrow] = (_Float16)acc1[mt][nf][r];
  #pragma unroll
  for (int mt = 0; mt < 2; ++mt)
    #pragma unroll
    for (int ks = 0; ks < 2; ++ks)
      a2[mt][ks] = *(const f16x8*)&rt[(mt*16 + lrow)*72 + ks*32 + lhi*8];

  f32x4 acc2[2][4];
  #pragma unroll
  for (int mt = 0; mt < 2; ++mt)
    #pragma unroll
    for (int nf = 0; nf < 4; ++nf) acc2[mt][nf] = (f32x4){0.f,0.f,0.f,0.f};
  #pragma unroll
  for (int nf = 0; nf < 4; ++nf)
    #pragma unroll
    for (int ks = 0; ks < 2; ++ks) {
      f16x8 b = *(const f16x8*)(fb2 + (nf*2 + ks)*512 + l*8);
      #pragma unroll
      for (int mt = 0; mt < 2; ++mt)
        acc2[mt][nf] = __builtin_amdgcn_mfma_f32_16x16x32_f16(a2[mt][ks], b, acc2[mt][nf], 0,0,0);
    }
  #pragma unroll
  for (int mt = 0; mt < 2; ++mt)
    #pragma unroll
    for (int nf = 0; nf < 4; ++nf)
      #pragma unroll
      for (int r = 0; r < 4; ++r) acc2[mt][nf][r] = siluf(acc2[mt][nf][r]);

  f16x8 a3[2][2];
  #pragma unroll
  for (int mt = 0; mt < 2; ++mt)
    #pragma unroll
    for (int nf = 0; nf < 4; ++nf)
      #pragma unroll
      for (int r = 0; r < 4; ++r)
        rt[(mt*16 + lhi*4 + r)*72 + nf*16 + lrow] = (_Float16)acc2[mt][nf][r];
  #pragma unroll
  for (int mt = 0; mt < 2; ++mt)
    #pragma unroll
    for (int ks = 0; ks < 2; ++ks)
      a3[mt][ks] = *(const f16x8*)&rt[(mt*16 + lrow)*72 + ks*32 + lhi*8];

  #pragma unroll
  for (int cc = 0; cc < 4; ++cc) {
    f32x4 acc3[NQ][2];
    #pragma unroll
    for (int q = 0; q < NQ; ++q)
      #pragma unroll
      for (int mt = 0; mt < 2; ++mt) acc3[q][mt] = (f32x4){0.f,0.f,0.f,0.f};
    #pragma unroll
    for (int q = 0; q < NQ; ++q) {
      const int nf3 = q*4 + cc;
      #pragma unroll
      for (int ks = 0; ks < 2; ++ks) {
        f16x8 b = *(const f16x8*)(fb3 + ((size_t)nf3*2 + ks)*512 + l*8);
        #pragma unroll
        for (int mt = 0; mt < 2; ++mt)
          acc3[q][mt] = __builtin_amdgcn_mfma_f32_16x16x32_f16(a3[mt][ks], b, acc3[q][mt], 0,0,0);
      }
    }
    const int cbase = (cc*16 + lrow)*NQ;
    #pragma unroll
    for (int mt = 0; mt < 2; ++mt)
      #pragma unroll
      for (int r = 0; r < 4; ++r) {
        const size_t rowoff = (size_t)(e0 + mt*16 + lhi*4 + r)*(NF3*16) + cbase;
        if constexpr (NQ == 4) {
          u16x4 pk;
          #pragma unroll
          for (int q = 0; q < 4; ++q) pk[q] = f2h(acc3[q][mt][r]);
          *(u16x4*)(wbuf + rowoff) = pk;
        } else {
          u16x2 pk;
          #pragma unroll
          for (int q = 0; q < 2; ++q) pk[q] = f2h(acc3[q][mt][r]);
          *(u16x2*)(wbuf + rowoff) = pk;
        }
      }
  }
}

// ---------------- generic f16 MFMA GEMM; optional f16 output ----------------
template<int KS, int NF, bool F16OUT>
__global__ __launch_bounds__(512, 4) void k_gemm(
    const float* __restrict__ A, int rstride, int M,
    const u16* __restrict__ fB, void* __restrict__ Ov) {
  __shared__ __align__(16) _Float16 lB[NF*KS*512];
  const int tid = threadIdx.x;
  const int w = tid >> 6, l = tid & 63;
  const int lrow = l & 15, lhi = l >> 4;
  const int n0 = blockIdx.x*128 + w*16;
  for (int i = tid; i < NF*KS*64; i += 512)
    *(f16x8*)&lB[(size_t)i*8] = *(const f16x8*)&fB[(size_t)i*8];
  f16x8 a[KS];
  {
    int row = n0 + lrow; if (row > M-1) row = M-1;
    #pragma unroll
    for (int ks = 0; ks < KS; ++ks)
      a[ks] = cvt8(A + (size_t)row*rstride + ks*32 + lhi*8);
  }
  __syncthreads();
  f32x4 acc[NF];
  #pragma unroll
  for (int nf = 0; nf < NF; ++nf) acc[nf] = (f32x4){0.f,0.f,0.f,0.f};
  #pragma unroll
  for (int nf = 0; nf < NF; ++nf)
    #pragma unroll
    for (int ks = 0; ks < KS; ++ks) {
      f16x8 b = *(const f16x8*)&lB[((size_t)(nf*KS + ks))*512 + l*8];
      acc[nf] = __builtin_amdgcn_mfma_f32_16x16x32_f16(a[ks], b, acc[nf], 0,0,0);
    }
  #pragma unroll
  for (int nf = 0; nf < NF; ++nf)
    #pragma unroll
    for (int r = 0; r < 4; ++r) {
      int row = n0 + lhi*4 + r;
      if (row < M) {
        size_t idx = (size_t)row*(NF*16) + nf*16 + lrow;
        if constexpr (F16OUT) ((u16*)Ov)[idx] = f2h(acc[nf][r]);
        else                  ((float*)Ov)[idx] = acc[nf][r];
      }
    }
}

// ---------------- sc partial (f16) ----------------
template<int KSO>
__global__ __launch_bounds__(512, 4) void k_scp(
    const float* __restrict__ Ao, const float* __restrict__ na,
    const u16* __restrict__ fBc, float* __restrict__ part) {
  __shared__ __align__(16) _Float16 lB[KSO*4096];
  const int tid = threadIdx.x;
  const int w = tid >> 6, l = tid & 63;
  const int lrow = l & 15, lhi = l >> 4;
  const int n0 = blockIdx.x*128 + w*16;
  const int vp = blockIdx.y;

  f16x8 ao[KSO];
  {
    int row = n0 + lrow; if (row > N_NODES-1) row = N_NODES-1;
    #pragma unroll
    for (int ks = 0; ks < KSO; ++ks)
      ao[ks] = cvt8(Ao + (size_t)row*(KSO*32) + ks*32 + lhi*8);
  }

  f32x4 acc[8];
  #pragma unroll
  for (int nf = 0; nf < 8; ++nf) acc[nf] = (f32x4){0.f,0.f,0.f,0.f};

  #pragma unroll
  for (int c = 0; c < 2; ++c) {
    const int v = vp*2 + c;
    __syncthreads();
    for (int i = tid; i < KSO*512; i += 512) {
      int gl = i & 63;
      int rest = i >> 6;
      int ks = rest % KSO;
      int nf = rest / KSO;
      size_t src = (((size_t)(v*8 + nf)*KSO + ks)*64 + gl)*8;
      *(f16x8*)&lB[(size_t)i*8] = *(const f16x8*)&fBc[src];
    }
    __syncthreads();
    f32x4 dacc[8];
    #pragma unroll
    for (int nf = 0; nf < 8; ++nf) dacc[nf] = (f32x4){0.f,0.f,0.f,0.f};
    #pragma unroll
    for (int nf = 0; nf < 8; ++nf)
      #pragma unroll
      for (int ks = 0; ks < KSO; ++ks) {
        f16x8 b = *(const f16x8*)&lB[((size_t)(nf*KSO + ks))*512 + l*8];
        dacc[nf] = __builtin_amdgcn_mfma_f32_16x16x32_f16(ao[ks], b, dacc[nf], 0,0,0);
      }
    #pragma unroll
    for (int r = 0; r < 4; ++r) {
      int row = n0 + lhi*4 + r; if (row > N_NODES-1) row = N_NODES-1;
      float nav = na[(size_t)row*16 + v];
      #pragma unroll
      for (int nf = 0; nf < 8; ++nf) acc[nf][r] += nav * dacc[nf][r];
    }
  }

  float* pp = part + (size_t)vp*NM128;
  #pragma unroll
  for (int nf = 0; nf < 8; ++nf)
    #pragma unroll
    for (int r = 0; r < 4; ++r) {
      int row = n0 + lhi*4 + r;
      if (row < N_NODES) pp[(size_t)row*128 + nf*16 + lrow] = acc[nf][r];
    }
}

// ---------------- fused reduce(9) + gating ----------------
__global__ void k_redgate(const float* __restrict__ part, const float* __restrict__ ov,
                          float* __restrict__ gs_out, float* __restrict__ gv) {
  int t = blockIdx.x*256 + threadIdx.x;
  if (t >= N_NODES*64) return;
  int n = t >> 6, v = t & 63;
  float o1 = 0.f, o2 = 0.f;
  #pragma unroll
  for (int p = 0; p < 9; ++p) {
    const float* pp = part + (size_t)p*NM128 + (size_t)n*128;
    o1 += pp[v]; o2 += pp[64+v];
  }
  float g = siluf(o1), gate = sigf(o2);
  gs_out[(size_t)n*64+v] = g;
  gv[(size_t)n*192 + 0*64 + v] = gate*ov[(size_t)n*192 + 0*64 + v];
  gv[(size_t)n*192 + 1*64 + v] = gate*ov[(size_t)n*192 + 1*64 + v];
  gv[(size_t)n*192 + 2*64 + v] = gate*ov[(size_t)n*192 + 2*64 + v];
}

// ---------------- fused reduce(9) + pooled accumulation (RLE) ----------------
__global__ __launch_bounds__(128) void k_redpool(
    const float* __restrict__ part, const int* __restrict__ batch,
    float* __restrict__ pool) {
  const int j = threadIdx.x;
  const int n0 = blockIdx.x*4;
  float outv[4];
  #pragma unroll
  for (int nn = 0; nn < 4; ++nn) {
    float sv = 0.f;
    #pragma unroll
    for (int p = 0; p < 9; ++p)
      sv += part[(size_t)p*NM128 + (size_t)(n0+nn)*128 + j];
    outv[nn] = sv;
  }
  int b0 = batch[n0], b1 = batch[n0+1], b2 = batch[n0+2], b3 = batch[n0+3];
  float sum = outv[0]; int cur = b0;
  if (b1 == cur) sum += outv[1]; else { atomicAdd(&pool[cur*128+j], sum); cur = b1; sum = outv[1]; }
  if (b2 == cur) sum += outv[2]; else { atomicAdd(&pool[cur*128+j], sum); cur = b2; sum = outv[2]; }
  if (b3 == cur) sum += outv[3]; else { atomicAdd(&pool[cur*128+j], sum); cur = b3; sum = outv[3]; }
  atomicAdd(&pool[cur*128+j], sum);
}

// ---------------- conv1 gather: sequential CSR stream; h in f16 ----------------
__global__ __launch_bounds__(256) void k_gather1(
    const u16* __restrict__ wbuf, const float* __restrict__ shv,
    const int* __restrict__ esrcp, const int* __restrict__ offs,
    const u16* __restrict__ h16,
    float* __restrict__ n_s, float* __restrict__ n_v) {
  const int wave = threadIdx.x >> 6, lane = threadIdx.x & 63;
  const int n = blockIdx.x*4 + wave;
  if (n >= N_NODES) return;
  const int s0 = offs[n], s1 = offs[n+1];
  float ns0=0.f, ns1=0.f;
  float nv00=0.f,nv01=0.f,nv02=0.f, nv10=0.f,nv11=0.f,nv12=0.f;
  for (int s = s0; s < s1; ++s) {
    int src = esrcp[s];
    u16x4 wv = *(const u16x4*)(wbuf + (size_t)s*256 + lane*4);
    float c0 = h2f(wv[0]), c1 = h2f(wv[1]), c2 = h2f(wv[2]), c3 = h2f(wv[3]);
    float h0 = h2f(h16[(size_t)src*128+lane]), h1 = h2f(h16[(size_t)src*128+64+lane]);
    float sv0 = shv[(size_t)s*3+0], sv1 = shv[(size_t)s*3+1], sv2 = shv[(size_t)s*3+2];
    ns0 += c0*h0; ns1 += c1*h1;
    float t0 = c2*h0, t1 = c3*h1;
    nv00 += t0*sv0; nv01 += t0*sv1; nv02 += t0*sv2;
    nv10 += t1*sv0; nv11 += t1*sv1; nv12 += t1*sv2;
  }
  n_s[n*128+lane]    = ns0*INV_SQRT10;
  n_s[n*128+64+lane] = ns1*INV_SQRT10;
  float* nvp = n_v + (size_t)n*384;      // [3][128]
  nvp[0*128+lane]    = nv00*INV_SQRT10;
  nvp[1*128+lane]    = nv01*INV_SQRT10;
  nvp[2*128+lane]    = nv02*INV_SQRT10;
  nvp[0*128+64+lane] = nv10*INV_SQRT10;
  nvp[1*128+64+lane] = nv11*INV_SQRT10;
  nvp[2*128+64+lane] = nv12*INV_SQRT10;
}

// ---------------- conv2 gather: sequential CSR stream; hs/hv in f16 ----------------
__global__ __launch_bounds__(256) void k_gather2(
    const u16* __restrict__ wbuf, const float* __restrict__ shv,
    const int* __restrict__ esrcp, const int* __restrict__ offs,
    const u16* __restrict__ hs16, const u16* __restrict__ hv16,
    float* __restrict__ n_mid) {
  const int wave = threadIdx.x >> 6, lane = threadIdx.x & 63;
  const int n = blockIdx.x*4 + wave;
  if (n >= N_NODES) return;
  const int s0 = offs[n], s1 = offs[n+1];
  float acc0 = 0.f, acc1 = 0.f;
  for (int s = s0; s < s1; ++s) {
    int src = esrcp[s];
    u16x2 wv = *(const u16x2*)(wbuf + (size_t)s*128 + lane*2);
    float w0 = h2f(wv[0]), w1 = h2f(wv[1]);
    float hs = h2f(hs16[(size_t)src*64+lane]);
    const u16* hvp = hv16 + (size_t)src*192;
    float sv0 = shv[(size_t)s*3+0], sv1 = shv[(size_t)s*3+1], sv2 = shv[(size_t)s*3+2];
    float dot = h2f(hvp[lane])*sv0 + h2f(hvp[64+lane])*sv1 + h2f(hvp[128+lane])*sv2;
    acc0 += w0*hs;
    acc1 += w1*dot;
  }
  n_mid[n*128+lane]    = acc0*INV_SQRT10;
  n_mid[n*128+64+lane] = acc1*INV_SQRT3*INV_SQRT10;
}

// ======== FALLBACK (atomic) kernels — used only if ws too small ========
__global__ __launch_bounds__(512) void k_edge1_at(
    const float* __restrict__ es8, const float* __restrict__ shv,
    const int* __restrict__ esrc, const int* __restrict__ edst,
    const float* __restrict__ h,
    const float* __restrict__ W0, const float* __restrict__ W1, const float* __restrict__ W2,
    float* __restrict__ n_s, float* __restrict__ n_v) {
  __shared__ float lW0[512];
  __shared__ float lW1[4096];
  __shared__ float lW2[16384];
  __shared__ float lA[8][64];
  __shared__ float lB[8][64];
  for (int i = threadIdx.x; i < 512;   i += 512) lW0[i] = W0[i];
  for (int i = threadIdx.x; i < 4096;  i += 512) lW1[i] = W1[i];
  for (int i = threadIdx.x; i < 16384; i += 512) lW2[i] = W2[i];
  __syncthreads();
  const int wave = threadIdx.x >> 6, lane = threadIdx.x & 63;
  const int nw = gridDim.x * 8;
  const int e0 = blockIdx.x*8 + wave;
  const int iters = (N_EDGES + nw - 1) / nw;
  for (int it = 0; it < iters; ++it) {
    int e = e0 + it*nw;
    bool valid = e < N_EDGES;
    float a = 0.f, sv0=0.f, sv1=0.f, sv2=0.f;
    int src = 0, dst = 0;
    if (valid) {
      const float* ep = es8 + e*8;
      sv0 = shv[e*3+0]; sv1 = shv[e*3+1]; sv2 = shv[e*3+2];
      src = esrc[e]; dst = edst[e];
      a = ep[0]*lW0[lane]      + ep[1]*lW0[64+lane]  + ep[2]*lW0[128+lane] + ep[3]*lW0[192+lane]
        + ep[4]*lW0[256+lane]  + ep[5]*lW0[320+lane] + ep[6]*lW0[384+lane] + ep[7]*lW0[448+lane];
      a = siluf(a * INV_SQRT8);
    }
    lA[wave][lane] = a;
    __syncthreads();
    {
      float b0=0.f;
      #pragma unroll
      for (int k = 0; k < 64; ++k) b0 += lA[wave][k]*lW1[k*64+lane];
      lB[wave][lane] = siluf(b0 * INV_SQRT64);
    }
    __syncthreads();
    if (valid) {
      float c0=0.f,c1=0.f,c2=0.f,c3=0.f;
      #pragma unroll
      for (int k = 0; k < 64; ++k) {
        float bk = lB[wave][k];
        const float* r = lW2 + k*256;
        c0 += bk*r[lane]; c1 += bk*r[64+lane]; c2 += bk*r[128+lane]; c3 += bk*r[192+lane];
      }
      float hs0 = h[src*128 + lane];
      float hs1 = h[src*128 + 64 + lane];
      atomicAdd(&n_s[dst*128 + lane],      c0*INV_SQRT64*hs0*INV_SQRT10);
      atomicAdd(&n_s[dst*128 + 64 + lane], c1*INV_SQRT64*hs1*INV_SQRT10);
      float t0 = c2*INV_SQRT64*hs0*INV_SQRT10;
      float t1 = c3*INV_SQRT64*hs1*INV_SQRT10;
      float* nvp = n_v + dst*384;
      atomicAdd(nvp + lane*3+0, t0*sv0);
      atomicAdd(nvp + lane*3+1, t0*sv1);
      atomicAdd(nvp + lane*3+2, t0*sv2);
      atomicAdd(nvp + (64+lane)*3+0, t1*sv0);
      atomicAdd(nvp + (64+lane)*3+1, t1*sv1);
      atomicAdd(nvp + (64+lane)*3+2, t1*sv2);
    }
  }
}

__global__ __launch_bounds__(512) void k_edge2_at(
    const float* __restrict__ es8, const float* __restrict__ shv,
    const int* __restrict__ esrc, const int* __restrict__ edst,
    const float* __restrict__ h_s, const float* __restrict__ h_v,
    const float* __restrict__ W0, const float* __restrict__ W1, const float* __restrict__ W2,
    float* __restrict__ n_mid) {
  __shared__ float lW0[512];
  __shared__ float lW1[4096];
  __shared__ float lW2[8192];
  __shared__ float lA[8][64];
  __shared__ float lB[8][64];
  for (int i = threadIdx.x; i < 512;  i += 512) lW0[i] = W0[i];
  for (int i = threadIdx.x; i < 4096; i += 512) lW1[i] = W1[i];
  for (int i = threadIdx.x; i < 8192; i += 512) lW2[i] = W2[i];
  __syncthreads();
  const int wave = threadIdx.x >> 6, lane = threadIdx.x & 63;
  const int nw = gridDim.x * 8;
  const int e0 = blockIdx.x*8 + wave;
  const int iters = (N_EDGES + nw - 1) / nw;
  for (int it = 0; it < iters; ++it) {
    int e = e0 + it*nw;
    bool valid = e < N_EDGES;
    float a = 0.f, sv0=0.f, sv1=0.f, sv2=0.f;
    int src = 0, dst = 0;
    if (valid) {
      const float* ep = es8 + e*8;
      sv0 = shv[e*3+0]; sv1 = shv[e*3+1]; sv2 = shv[e*3+2];
      src = esrc[e]; dst = edst[e];
      a = ep[0]*lW0[lane]      + ep[1]*lW0[64+lane]  + ep[2]*lW0[128+lane] + ep[3]*lW0[192+lane]
        + ep[4]*lW0[256+lane]  + ep[5]*lW0[320+lane] + ep[6]*lW0[384+lane] + ep[7]*lW0[448+lane];
      a = siluf(a * INV_SQRT8);
    }
    lA[wave][lane] = a;
    __syncthreads();
    {
      float b0=0.f;
      #pragma unroll
      for (int k = 0; k < 64; ++k) b0 += lA[wave][k]*lW1[k*64+lane];
      lB[wave][lane] = siluf(b0 * INV_SQRT64);
    }
    __syncthreads();
    if (valid) {
      float c0=0.f, c1=0.f;
      #pragma unroll
      for (int k = 0; k < 64; ++k) {
        float bk = lB[wave][k];
        const float* r = lW2 + k*128;
        c0 += bk*r[lane]; c1 += bk*r[64+lane];
      }
      float hsv = h_s[src*64 + lane];
      const float* hvp = h_v + src*192 + lane*3;
      float dotv = hvp[0]*sv0 + hvp[1]*sv1 + hvp[2]*sv2;
      atomicAdd(&n_mid[dst*128 + lane],      c0*INV_SQRT64*hsv*INV_SQRT10);
      atomicAdd(&n_mid[dst*128 + 64 + lane], c1*INV_SQRT64*dotv*INV_SQRT3*INV_SQRT10);
    }
  }
}

// ---------------- FALLBACK conv1 node pass (full, old n_v layout) ----------------
__global__ __launch_bounds__(128) void k_node1(
    const float* __restrict__ n_s, const float* __restrict__ n_v,
    const float* __restrict__ s,   const float* __restrict__ na,
    const float* __restrict__ Wls, const float* __restrict__ Wlv,
    const float* __restrict__ Csc, const float* __restrict__ W2s, const float* __restrict__ W2v,
    float* __restrict__ gs_out, float* __restrict__ hs_out, float* __restrict__ hv_out) {
  __shared__ float l_ns[512], l_s[512], l_na[64], l_nv[1536];
  __shared__ float l_outs[512], l_ov[768], l_gs[256], l_gv[768];
  const int j = threadIdx.x;
  const int n0 = blockIdx.x*4;
  for (int i = j; i < 512;  i += 128) { l_ns[i] = n_s[n0*128+i]; l_s[i] = s[n0*128+i]; }
  for (int i = j; i < 1536; i += 128) l_nv[i] = n_v[n0*384+i];
  if (j < 64) l_na[j] = na[n0*16+j];
  __syncthreads();

  float accs[4] = {0.f,0.f,0.f,0.f};
  for (int k = 0; k < 128; ++k) {
    float w = Wls[k*128+j];
    accs[0] += l_ns[k]*w; accs[1] += l_ns[128+k]*w;
    accs[2] += l_ns[256+k]*w; accs[3] += l_ns[384+k]*w;
  }
  float accc[4] = {0.f,0.f,0.f,0.f};
  for (int vt = 0; vt < 16; vt += 4) {
    float a0[4],a1[4],a2[4],a3[4];
    #pragma unroll
    for (int n = 0; n < 4; ++n) {
      a0[n]=l_na[n*16+vt]; a1[n]=l_na[n*16+vt+1];
      a2[n]=l_na[n*16+vt+2]; a3[n]=l_na[n*16+vt+3];
    }
    for (int u = 0; u < 128; ++u) {
      const float* cp = Csc + (u*16+vt)*128 + j;
      float c0=cp[0], c1=cp[128], c2=cp[256], c3=cp[384];
      float s0=l_s[u], s1=l_s[128+u], s2=l_s[256+u], s3=l_s[384+u];
      accc[0] += s0*(a0[0]*c0 + a1[0]*c1 + a2[0]*c2 + a3[0]*c3);
      accc[1] += s1*(a0[1]*c0 + a1[1]*c1 + a2[1]*c2 + a3[1]*c3);
      accc[2] += s2*(a0[2]*c0 + a1[2]*c1 + a2[2]*c2 + a3[2]*c3);
      accc[3] += s3*(a0[3]*c0 + a1[3]*c1 + a2[3]*c2 + a3[3]*c3);
    }
  }
  #pragma unroll
  for (int n = 0; n < 4; ++n)
    l_outs[n*128+j] = accs[n]*INV_SQRT128 + accc[n]*INV_SQRT2048;

  const int jj = j & 63, hh = j >> 6;
  float ov[2][3] = {{0.f,0.f,0.f},{0.f,0.f,0.f}};
  for (int u = 0; u < 128; ++u) {
    float w = Wlv[u*64+jj];
    #pragma unroll
    for (int t = 0; t < 2; ++t) {
      int n = 2*hh+t;
      ov[t][0] += l_nv[n*384+u*3+0]*w;
      ov[t][1] += l_nv[n*384+u*3+1]*w;
      ov[t][2] += l_nv[n*384+u*3+2]*w;
    }
  }
  #pragma unroll
  for (int t = 0; t < 2; ++t) {
    int n = 2*hh+t;
    l_ov[n*192+jj*3+0] = ov[t][0]*INV_SQRT128;
    l_ov[n*192+jj*3+1] = ov[t][1]*INV_SQRT128;
    l_ov[n*192+jj*3+2] = ov[t][2]*INV_SQRT128;
  }
  __syncthreads();

  #pragma unroll
  for (int t = 0; t < 2; ++t) {
    int n = 2*hh+t;
    float gv_s = siluf(l_outs[n*128+jj]);
    float gate = sigf (l_outs[n*128+64+jj]);
    l_gs[n*64+jj] = gv_s;
    gs_out[(n0+n)*64+jj] = gv_s;
    l_gv[n*192+jj*3+0] = gate*l_ov[n*192+jj*3+0];
    l_gv[n*192+jj*3+1] = gate*l_ov[n*192+jj*3+1];
    l_gv[n*192+jj*3+2] = gate*l_ov[n*192+jj*3+2];
  }
  __syncthreads();

  float ha[2] = {0.f,0.f};
  for (int k = 0; k < 64; ++k) {
    float w = W2s[k*64+jj];
    ha[0] += l_gs[(2*hh+0)*64+k]*w;
    ha[1] += l_gs[(2*hh+1)*64+k]*w;
  }
  hs_out[(n0+2*hh+0)*64+jj] = ha[0]*INV_SQRT64;
  hs_out[(n0+2*hh+1)*64+jj] = ha[1]*INV_SQRT64;

  float hv[2][3] = {{0.f,0.f,0.f},{0.f,0.f,0.f}};
  for (int u = 0; u < 64; ++u) {
    float w = W2v[u*64+jj];
    #pragma unroll
    for (int t = 0; t < 2; ++t) {
      int n = 2*hh+t;
      hv[t][0] += l_gv[n*192+u*3+0]*w;
      hv[t][1] += l_gv[n*192+u*3+1]*w;
      hv[t][2] += l_gv[n*192+u*3+2]*w;
    }
  }
  #pragma unroll
  for (int t = 0; t < 2; ++t) {
    int n = 2*hh+t;
    hv_out[(n0+n)*192+jj*3+0] = hv[t][0]*INV_SQRT64;
    hv_out[(n0+n)*192+jj*3+1] = hv[t][1]*INV_SQRT64;
    hv_out[(n0+n)*192+jj*3+2] = hv[t][2]*INV_SQRT64;
  }
}

// ---------------- FALLBACK conv2 node pass + pooling ----------------
__global__ __launch_bounds__(128) void k_node2(
    const float* __restrict__ n_mid, const float* __restrict__ gs,
    const float* __restrict__ na, const int* __restrict__ batch,
    const float* __restrict__ W, const float* __restrict__ Csc,
    float* __restrict__ pool) {
  __shared__ float l_nm[512], l_gs[256], l_na[64];
  const int j = threadIdx.x;
  const int n0 = blockIdx.x*4;
  for (int i = j; i < 512; i += 128) l_nm[i] = n_mid[n0*128+i];
  for (int i = j; i < 256; i += 128) l_gs[i] = gs[n0*64+i];
  if (j < 64) l_na[j] = na[n0*16+j];
  __syncthreads();
  float acc[4] = {0.f,0.f,0.f,0.f};
  for (int k = 0; k < 128; ++k) {
    float w = W[k*128+j];
    acc[0] += l_nm[k]*w; acc[1] += l_nm[128+k]*w;
    acc[2] += l_nm[256+k]*w; acc[3] += l_nm[384+k]*w;
  }
  float acc2[4] = {0.f,0.f,0.f,0.f};
  for (int vt = 0; vt < 16; vt += 4) {
    float a0[4],a1[4],a2[4],a3[4];
    #pragma unroll
    for (int n = 0; n < 4; ++n) {
      a0[n]=l_na[n*16+vt]; a1[n]=l_na[n*16+vt+1];
      a2[n]=l_na[n*16+vt+2]; a3[n]=l_na[n*16+vt+3];
    }
    for (int u = 0; u < 64; ++u) {
      const float* cp = Csc + (u*16+vt)*128 + j;
      float c0=cp[0], c1=cp[128], c2=cp[256], c3=cp[384];
      float s0=l_gs[u], s1=l_gs[64+u], s2=l_gs[128+u], s3=l_gs[192+u];
      acc2[0] += s0*(a0[0]*c0 + a1[0]*c1 + a2[0]*c2 + a3[0]*c3);
      acc2[1] += s1*(a0[1]*c0 + a1[1]*c1 + a2[1]*c2 + a3[1]*c3);
      acc2[2] += s2*(a0[2]*c0 + a1[2]*c1 + a2[2]*c2 + a3[2]*c3);
      acc2[3] += s3*(a0[3]*c0 + a1[3]*c1 + a2[3]*c2 + a3[3]*c3);
    }
  }
  float outv[4];
  #pragma unroll
  for (int n = 0; n < 4; ++n)
    outv[n] = acc[n]*INV_SQRT128 + acc2[n]*INV_SQRT1024;
  int b0 = batch[n0], b1 = batch[n0+1], b2 = batch[n0+2], b3 = batch[n0+3];
  float sum = outv[0]; int cur = b0;
  if (b1 == cur) sum += outv[1]; else { atomicAdd(&pool[cur*128+j], sum); cur = b1; sum = outv[1]; }
  if (b2 == cur) sum += outv[2]; else { atomicAdd(&pool[cur*128+j], sum); cur = b2; sum = outv[2]; }
  if (b3 == cur) sum += outv[3]; else { atomicAdd(&pool[cur*128+j], sum); cur = b3; sum = outv[3]; }
  atomicAdd(&pool[cur*128+j], sum);
}

// ---------------- readout head: one block per graph, wave-parallel reduce ----------------
__global__ __launch_bounds__(128) void k_head(
    const float* __restrict__ pool, const float* __restrict__ cnt,
    const float* __restrict__ Wr1, const float* __restrict__ Wr2,
    float* __restrict__ out) {
  __shared__ float lp[128];
  __shared__ float wsum[2];
  const int j = threadIdx.x;
  const int g = blockIdx.x;
  float inv = 1.f / fmaxf(cnt[g], 1.f);
  lp[j] = pool[(size_t)g*128 + j]*inv;
  __syncthreads();
  float acc = 0.f;
  for (int k = 0; k < 128; ++k) acc += lp[k]*Wr1[k*128+j];
  float val = siluf(acc*INV_SQRT128) * Wr2[j];
  #pragma unroll
  for (int d = 32; d > 0; d >>= 1) val += __shfl_down(val, d);
  if ((j & 63) == 0) wsum[j >> 6] = val;
  __syncthreads();
  if (j == 0) out[g] = (wsum[0] + wsum[1]) * INV_SQRT128;
}

extern "C" void kernel_launch(void* const* d_in, const int* in_sizes, int n_in,
                              void* d_out, int out_size, void* d_ws, size_t ws_size,
                              hipStream_t stream) {
  const float* x         = (const float*)d_in[0];
  const float* node_attr = (const float*)d_in[1];
  const int*   esrc      = (const int*)d_in[2];
  const int*   edst      = (const int*)d_in[3];
  const float* evec      = (const float*)d_in[4];
  const int*   batch     = (const int*)d_in[5];
  const float* W_embed   = (const float*)d_in[6];
  const float* c1_lin1   = (const float*)d_in[7];
  const float* c1_fc_w0  = (const float*)d_in[8];
  const float* c1_fc_w1  = (const float*)d_in[9];
  const float* c1_fc_w2  = (const float*)d_in[10];
  const float* c1_lin2_s = (const float*)d_in[11];
  const float* c1_lin2_v = (const float*)d_in[12];
  const float* c1_sc     = (const float*)d_in[13];
  const float* c2_lin1_s = (const float*)d_in[14];
  const float* c2_lin1_v = (const float*)d_in[15];
  const float* c2_fc_w0  = (const float*)d_in[16];
  const float* c2_fc_w1  = (const float*)d_in[17];
  const float* c2_fc_w2  = (const float*)d_in[18];
  const float* c2_lin2   = (const float*)d_in[19];
  const float* c2_sc     = (const float*)d_in[20];
  const float* Wr1       = (const float*)d_in[21];
  const float* Wr2       = (const float*)d_in[22];

  float* ws    = (float*)d_ws;
  float* es8   = ws + OFF_ES8;          // f32 view (fallback)
  u16*   es8h_ = (u16*)es8;             // f16 view (big path)
  float* shv   = ws + OFF_SHV;
  float* s_    = ws + OFF_S;
  float* h_    = ws + OFF_H;
  u16*   h16_  = (u16*)h_;
  float* gs_   = ws + OFF_GS;
  float* hs_   = ws + OFF_HS;
  u16*   hs16_ = (u16*)hs_;
  float* hv_   = ws + OFF_HV;
  u16*   hv16_ = (u16*)hv_;
  float* ns_   = ws + OFF_NS;
  float* nv_   = ws + OFF_NV;
  float* nmid_ = ws + OFF_NMID;
  float* pool_ = ws + OFF_POOL;
  float* cnt_  = ws + OFF_CNT;
  int*   hist_ = (int*)(ws + OFF_HIST);
  int*   curs_ = (int*)(ws + OFF_CURS);
  int*   offs_ = (int*)(ws + OFF_OFFS);
  u16*   frag_ = (u16*)(ws + OFF_FRAG);
  int*   esrcp_= (int*)(ws + OFF_SLOT);
  float* wbuf_ = ws + OFF_WBUF;
  u16*   wb16_ = (u16*)wbuf_;

  // upper-wbuf carve-outs
  float* out1_  = wbuf_ + (size_t)N_EDGES*128;                 // reserved (layout stability)
  u16*   nfrag_ = (u16*)(out1_ + (size_t)NM128);               // 442368 u16
  float* part_  = out1_ + (size_t)NM128 + NFRAG_TOT/2;         // 9 x 1.28M floats
  float* ov_    = part_ + (size_t)9*NM128;                     // 1.92M floats
  float* gv_    = nv_;                                         // aliases nv (dead after ov GEMM)

  const bool big = ws_size >= WS_NEED_BYTES;

  if (big) {
    hipMemsetAsync(pool_, 0, (size_t)(OFF_OFFS - OFF_POOL)*sizeof(float), stream);
    k_cnthist<<<(N_EDGES+255)/256, 256, 0, stream>>>(batch, edst, cnt_, hist_);
    k_scanp<<<1, 1024, 0, stream>>>(hist_, offs_);
    k_slotgeom<<<(N_EDGES+255)/256, 256, 0, stream>>>(edst, esrc, evec, offs_,
                                                      curs_, esrcp_, es8h_, shv);

    // single merged frag prep: all 15 weight tensors (f16 single-plane)
    {
      PDS m{};
      m.d[0]  = {c1_fc_w0,  frag_  + F_B1,   8,   64,   1, 2048,   INV_SQRT8};
      m.d[1]  = {c1_fc_w1,  frag_  + F_B2,   64,  64,   2, 4096,   INV_SQRT64};
      m.d[2]  = {c1_fc_w2,  frag_  + F_B3,   64,  256,  2, 16384,  INV_SQRT64};
      m.d[3]  = {c2_fc_w0,  frag_  + F_B1b,  8,   64,   1, 2048,   INV_SQRT8};
      m.d[4]  = {c2_fc_w1,  frag_  + F_B2b,  64,  64,   2, 4096,   INV_SQRT64};
      m.d[5]  = {c2_fc_w2,  frag_  + F_B3b,  64,  128,  2, 8192,   INV_SQRT64};
      m.d[6]  = {W_embed,   frag_  + F_WE,   32,  128,  1, 4096,   INV_SQRT32};
      m.d[7]  = {c1_lin1,   frag_  + F_L1,   128, 128,  4, 16384,  INV_SQRT128};
      m.d[8]  = {c1_lin2_s, nfrag_ + NF_WLS, 128, 128,  4, 16384,  INV_SQRT128};
      m.d[9]  = {c1_sc,     nfrag_ + NF_C1,  128, 2048, 4, 262144, INV_SQRT2048};
      m.d[10] = {c2_lin2,   nfrag_ + NF_W2,  128, 128,  4, 16384,  INV_SQRT128};
      m.d[11] = {c2_sc,     nfrag_ + NF_C2,  64,  2048, 2, 131072, INV_SQRT1024};
      m.d[12] = {c1_lin2_v, nfrag_ + NF_LV,  128, 64,   4, 8192,   INV_SQRT128};
      m.d[13] = {c2_lin1_s, nfrag_ + NF_2S,  64,  64,   2, 4096,   INV_SQRT64};
      m.d[14] = {c2_lin1_v, nfrag_ + NF_2V,  64,  64,   2, 4096,   INV_SQRT64};
      m.nd = 15; m.tot = FRAG_TOT + NFRAG_TOT;
      k_prepmulti<<<976, 256, 0, stream>>>(m);
    }

    // s = x@W_embed (f32 out) ; h = s@c1_lin1 (f16 out)
    k_gemm<1,8,false><<<79, 512, 0, stream>>>(x,  32,  N_NODES, frag_ + F_WE, s_);
    k_gemm<4,8,true ><<<79, 512, 0, stream>>>(s_, 128, N_NODES, frag_ + F_L1, h16_);

    // conv1 edge MLP (CSR-ordered) + streaming gather
    k_mlp<16><<<1250, 256, 0, stream>>>(es8h_, frag_ + F_B1, frag_ + F_B2, frag_ + F_B3, wb16_);
    k_gather1<<<(N_NODES+3)/4, 256, 0, stream>>>(wb16_, shv, esrcp_, offs_, h16_, ns_, nv_);

    // conv1 node: dense + sc partials -> fused reduce+gate
    k_gemm<4,8,false><<<79, 512, 0, stream>>>(ns_, 128, N_NODES, nfrag_ + NF_WLS, part_ + (size_t)8*NM128);
    k_scp<4><<<dim3(79,8), 512, 0, stream>>>(s_, node_attr, nfrag_ + NF_C1, part_);
    k_gemm<4,4,false><<<235, 512, 0, stream>>>(nv_, 128, N_NODES*3, nfrag_ + NF_LV, ov_);
    k_redgate<<<(N_NODES*64+255)/256, 256, 0, stream>>>(part_, ov_, gs_, gv_);
    k_gemm<2,4,true><<<79, 512, 0, stream>>>(gs_, 64, N_NODES, nfrag_ + NF_2S, hs16_);
    k_gemm<2,4,true><<<235, 512, 0, stream>>>(gv_, 64, N_NODES*3, nfrag_ + NF_2V, hv16_);

    // conv2 edge MLP + streaming gather
    k_mlp<8><<<1250, 256, 0, stream>>>(es8h_, frag_ + F_B1b, frag_ + F_B2b, frag_ + F_B3b, wb16_);
    k_gather2<<<(N_NODES+3)/4, 256, 0, stream>>>(wb16_, shv, esrcp_, offs_, hs16_, hv16_, nmid_);

    // conv2 node: partials -> fused reduce+pool
    k_gemm<4,8,false><<<79, 512, 0, stream>>>(nmid_, 128, N_NODES, nfrag_ + NF_W2, part_ + (size_t)8*NM128);
    k_scp<2><<<dim3(79,8), 512, 0, stream>>>(gs_, node_attr, nfrag_ + NF_C2, part_);
    k_redpool<<<N_NODES/4, 128, 0, stream>>>(part_, batch, pool_);
  } else {
    hipMemsetAsync(ns_, 0, (size_t)(OFF_HIST - OFF_NS)*sizeof(float), stream);
    k_geom_id<<<N_EDGES/256, 256, 0, stream>>>(evec, es8, shv);
    k_linear128<<<(N_NODES*128)/256, 256, 0, stream>>>(x,  W_embed, s_, 32,  INV_SQRT32,  N_NODES*128);
    k_linear128<<<(N_NODES*128)/256, 256, 0, stream>>>(s_, c1_lin1, h_, 128, INV_SQRT128, N_NODES*128);
    k_cnthist<<<(N_EDGES+255)/256, 256, 0, stream>>>(batch, edst, cnt_, hist_);
    k_edge1_at<<<256, 512, 0, stream>>>(es8, shv, esrc, edst, h_,
                                        c1_fc_w0, c1_fc_w1, c1_fc_w2, ns_, nv_);
    k_node1<<<N_NODES/4, 128, 0, stream>>>(ns_, nv_, s_, node_attr,
                                           c1_lin2_s, c1_lin2_v, c1_sc,
                                           c2_lin1_s, c2_lin1_v, gs_, hs_, hv_);
    k_edge2_at<<<512, 512, 0, stream>>>(es8, shv, esrc, edst, hs_, hv_,
                                        c2_fc_w0, c2_fc_w1, c2_fc_w2, nmid_);
    k_node2<<<N_NODES/4, 128, 0, stream>>>(nmid_, gs_, node_attr, batch,
                                           c2_lin2, c2_sc, pool_);
  }

  k_head<<<N_GRAPHS, 128, 0, stream>>>(pool_, cnt_, Wr1, Wr2, (float*)d_out);
}